// Round 22
// 1107.588 us; speedup vs baseline: 7.2320x; 1.0415x over previous
//
#include <hip/hip_runtime.h>
#include <hip/hip_bf16.h>
#include <math.h>

#define D_DIM 1024
#define B_ROWS 4096
#define M_ROWS 32768
#define TOPK 8
#define TOPC 16
#define TOPB 8
#define NCB (M_ROWS / 128)

typedef __attribute__((ext_vector_type(8))) short bf16x8;
typedef __attribute__((ext_vector_type(4))) float f32x4;

__device__ __forceinline__ unsigned short f32_to_bf16(float f) {
  unsigned int u = __float_as_uint(f);
  unsigned int r = (u + 0x7FFFu + ((u >> 16) & 1u)) >> 16;
  return (unsigned short)r;
}
__device__ __forceinline__ float bf16_to_f32(unsigned short h) {
  return __uint_as_float(((unsigned int)h) << 16);
}
__device__ __forceinline__ void async_copy16(void* lds, const void* g) {
  __builtin_amdgcn_global_load_lds(
      (const __attribute__((address_space(1))) unsigned int*)g,
      (__attribute__((address_space(3))) unsigned int*)lds, 16, 0, 0);
}

template <int N>
__device__ __forceinline__ void insN(float v, int idx,
                                     float* __restrict__ tv,
                                     int* __restrict__ ti) {
  if (v < tv[N - 1]) return;
  if (v == tv[N - 1] && idx > ti[N - 1]) return;
  float cv = v;
  int ci = idx;
#pragma unroll
  for (int p = 0; p < N; ++p) {
    if (cv > tv[p] || (cv == tv[p] && ci < ti[p])) {
      const float t0 = tv[p]; tv[p] = cv; cv = t0;
      const int t1 = ti[p]; ti[p] = ci; ci = t1;
    }
  }
}

// ---------------------------------------------------------------------------
// FUSED gram + bias terms (round-22). Blocks 0-255: G tile (round-21-proven
// dbuf body; f0=(blk>>4)*64, e0=(blk&15)*64). Blocks 256-259: wvec; 260-263:
// ubias; 264: s0 (round-20-proven bodies). Branch is block-uniform.
// ---------------------------------------------------------------------------
__global__ __launch_bounds__(256) void gram_bias(
    const float* __restrict__ Wq, const float* __restrict__ Wk,
    const float* __restrict__ bq, const float* __restrict__ bk,
    double* __restrict__ G, double* __restrict__ wvec,
    double* __restrict__ ubias, double* __restrict__ s0)
{
  __shared__ float sA[2][32][68];
  __shared__ float sB[2][32][68];
  const int blk = blockIdx.x;
  const int tid = threadIdx.x;

  if (blk < 256) {
    const int tx = tid & 15, ty = tid >> 4;
    const int f0 = (blk >> 4) * 64;
    const int e0 = (blk & 15) * 64;

    double acc[4][4];
#pragma unroll
    for (int i = 0; i < 4; ++i)
#pragma unroll
      for (int j = 0; j < 4; ++j) acc[i][j] = 0.0;

    auto STAGE = [&](int d, int k0) {
#pragma unroll
      for (int it = 0; it < 2; ++it) {
        const int L = it * 256 + tid;
        const int kk = L >> 4, c4 = (L & 15) * 4;
        *(float4*)&sA[d][kk][c4] = *(const float4*)(Wq + (size_t)(k0 + kk) * D_DIM + f0 + c4);
        *(float4*)&sB[d][kk][c4] = *(const float4*)(Wk + (size_t)(k0 + kk) * D_DIM + e0 + c4);
      }
    };

    STAGE(0, 0);
    __syncthreads();
    int cur = 0;
    for (int t = 0; t < 32; ++t) {
      if (t < 31) STAGE(cur ^ 1, (t + 1) * 32);
#pragma unroll
      for (int kk = 0; kk < 32; ++kk) {
        const double a[4] = {sA[cur][kk][ty * 4 + 0], sA[cur][kk][ty * 4 + 1],
                             sA[cur][kk][ty * 4 + 2], sA[cur][kk][ty * 4 + 3]};
        const double b[4] = {sB[cur][kk][tx * 4 + 0], sB[cur][kk][tx * 4 + 1],
                             sB[cur][kk][tx * 4 + 2], sB[cur][kk][tx * 4 + 3]};
#pragma unroll
        for (int i = 0; i < 4; ++i)
#pragma unroll
          for (int j = 0; j < 4; ++j)
            acc[i][j] = fma(a[i], b[j], acc[i][j]);
      }
      __syncthreads();
      cur ^= 1;
    }
#pragma unroll
    for (int i = 0; i < 4; ++i)
#pragma unroll
      for (int j = 0; j < 4; ++j)
        G[(size_t)(f0 + ty * 4 + i) * D_DIM + e0 + tx * 4 + j] = acc[i][j];
  } else if (blk < 260) {
    const int c = (blk - 256) * 256 + tid;
    double acc = 0.0;
    for (int n = 0; n < D_DIM; ++n)
      acc = fma((double)Wq[(size_t)n * D_DIM + c], (double)bk[n], acc);
    wvec[c] = acc;
  } else if (blk < 264) {
    const int c = (blk - 260) * 256 + tid;
    double acc = 0.0;
    for (int n = 0; n < D_DIM; ++n)
      acc = fma((double)Wk[(size_t)n * D_DIM + c], (double)bq[n], acc);
    ubias[c] = acc;
  } else {
    double acc = 0.0;
#pragma unroll
    for (int i = 0; i < 4; ++i) {
      const int idx = tid * 4 + i;
      acc = fma((double)bq[idx], (double)bk[idx], acc);
    }
#pragma unroll
    for (int off = 32; off > 0; off >>= 1) acc += __shfl_down(acc, off);
    __shared__ double red[4];
    if ((tid & 63) == 0) red[tid >> 6] = acc;
    __syncthreads();
    if (tid == 0) s0[0] = red[0] + red[1] + red[2] + red[3];
  }
}

// ---------------------------------------------------------------------------
// u[b,d] = sum_e query[b,e]*G[e,d] + ubias[d], f64 (round-20/21-proven dbuf).
// ---------------------------------------------------------------------------
__global__ __launch_bounds__(256) void uproj_G(
    const float* __restrict__ query, const double* __restrict__ G,
    const double* __restrict__ ubias, double* __restrict__ U)
{
  __shared__ double sAdT[2][32][66];
  __shared__ double sBd[2][32][68];
  const int tid = threadIdx.x;
  const int tx = tid & 15, ty = tid >> 4;
  const int row0 = blockIdx.x * 64;
  const int col0 = blockIdx.y * 64;

  double acc[4][4];
#pragma unroll
  for (int i = 0; i < 4; ++i)
#pragma unroll
    for (int j = 0; j < 4; ++j) acc[i][j] = 0.0;

  auto STAGE = [&](int d, int k0) {
#pragma unroll
    for (int it = 0; it < 2; ++it) {
      const int L = it * 256 + tid;
      const int rowa = L >> 3, c4 = (L & 7) * 4;
      const float4 v =
          *(const float4*)(query + (size_t)(row0 + rowa) * D_DIM + k0 + c4);
      sAdT[d][c4 + 0][rowa] = (double)v.x;
      sAdT[d][c4 + 1][rowa] = (double)v.y;
      sAdT[d][c4 + 2][rowa] = (double)v.z;
      sAdT[d][c4 + 3][rowa] = (double)v.w;
    }
#pragma unroll
    for (int it = 0; it < 4; ++it) {
      const int L = it * 256 + tid;
      const int kk = L >> 5, c2 = (L & 31) * 2;
      *(double2*)&sBd[d][kk][c2] =
          *(const double2*)(G + (size_t)(k0 + kk) * D_DIM + col0 + c2);
    }
  };

  STAGE(0, 0);
  __syncthreads();
  int cur = 0;
  for (int t = 0; t < 32; ++t) {
    if (t < 31) STAGE(cur ^ 1, (t + 1) * 32);
#pragma unroll
    for (int kk = 0; kk < 32; ++kk) {
      const double2 p0 = *(const double2*)&sAdT[cur][kk][ty * 4];
      const double2 p1 = *(const double2*)&sAdT[cur][kk][ty * 4 + 2];
      const double a[4] = {p0.x, p0.y, p1.x, p1.y};
      const double bb[4] = {sBd[cur][kk][tx * 4 + 0], sBd[cur][kk][tx * 4 + 1],
                            sBd[cur][kk][tx * 4 + 2], sBd[cur][kk][tx * 4 + 3]};
#pragma unroll
      for (int i = 0; i < 4; ++i)
#pragma unroll
        for (int j = 0; j < 4; ++j)
          acc[i][j] = fma(a[i], bb[j], acc[i][j]);
    }
    __syncthreads();
    cur ^= 1;
  }
  const double ub[4] = {ubias[col0 + tx * 4 + 0], ubias[col0 + tx * 4 + 1],
                        ubias[col0 + tx * 4 + 2], ubias[col0 + tx * 4 + 3]};
#pragma unroll
  for (int i = 0; i < 4; ++i) {
    const size_t base = (size_t)(row0 + ty * 4 + i) * D_DIM + col0 + tx * 4;
    *(double2*)(U + base)     = (double2){acc[i][0] + ub[0], acc[i][1] + ub[1]};
    *(double2*)(U + base + 2) = (double2){acc[i][2] + ub[2], acc[i][3] + ub[3]};
  }
}

// ---------------------------------------------------------------------------
// Fused sims + per-half top-4 (rounds 18-21 proven).
// ---------------------------------------------------------------------------
#define SBUF3 12288
__global__ __launch_bounds__(512, 4) void sims_topc_gemm(
    const unsigned short* __restrict__ A, const unsigned short* __restrict__ B,
    float* __restrict__ part_v, int* __restrict__ part_i)
{
  __shared__ unsigned short smem[3 * SBUF3];

  const int tid = threadIdx.x;
  const int lane = tid & 63;
  const int wave = tid >> 6;
  const int wr = wave >> 1;
  const int wc = wave & 1;

  const int bid = blockIdx.x;
  const int x = bid & 7;
  const int t9 = bid >> 3;
  const int cbg = t9 >> 7;
  const int r = (t9 >> 3) & 15;
  const int cbl = t9 & 7;
  const int cb = (x * 4 + cbg) * 8 + cbl;
  const int row0 = r * 256;
  const int col0 = cb * 128;

  const int st_r = lane >> 2;
  const int st_swz = ((lane & 3) ^ ((st_r >> 1) & 3)) * 16;

  auto STAGE = [&](int d, int k0) {
    unsigned short* buf = smem + d * SBUF3;
#pragma unroll
    for (int i = 0; i < 3; ++i) {
      const int seg = wave * 3 + i;
      if (seg < 16) {
        const int grow = row0 + seg * 16 + st_r;
        async_copy16((char*)(buf + seg * 512),
                     (const char*)(A + (size_t)grow * D_DIM + k0) + st_swz);
      } else {
        const int s2 = seg - 16;
        const int grow = col0 + s2 * 16 + st_r;
        async_copy16((char*)(buf + 8192 + s2 * 512),
                     (const char*)(B + (size_t)grow * D_DIM + k0) + st_swz);
      }
    }
  };

  f32x4 acc[4][4];
#pragma unroll
  for (int m = 0; m < 4; ++m)
#pragma unroll
    for (int n = 0; n < 4; ++n) acc[m][n] = (f32x4){0.f, 0.f, 0.f, 0.f};

  auto COMPUTE = [&](int d) {
    const unsigned short* sA = smem + d * SBUF3;
    const unsigned short* sB = sA + 8192;
    bf16x8 af[4], bfr[4];
    const int ch = lane >> 4;
#pragma unroll
    for (int m = 0; m < 4; ++m) {
      const int Ra = wr * 64 + m * 16 + (lane & 15);
      af[m] = *(const bf16x8*)((const char*)sA + Ra * 64 + ((ch ^ ((Ra >> 1) & 3)) * 16));
    }
#pragma unroll
    for (int n = 0; n < 4; ++n) {
      const int Rb = wc * 64 + n * 16 + (lane & 15);
      bfr[n] = *(const bf16x8*)((const char*)sB + Rb * 64 + ((ch ^ ((Rb >> 1) & 3)) * 16));
    }
    __builtin_amdgcn_s_setprio(1);
#pragma unroll
    for (int m = 0; m < 4; ++m)
#pragma unroll
      for (int n = 0; n < 4; ++n)
        acc[m][n] = __builtin_amdgcn_mfma_f32_16x16x32_bf16(af[m], bfr[n], acc[m][n], 0, 0, 0);
    __builtin_amdgcn_s_setprio(0);
  };

  STAGE(0, 0);
  STAGE(1, 32);
  asm volatile("s_waitcnt vmcnt(3)" ::: "memory");
  __builtin_amdgcn_sched_barrier(0);
  __builtin_amdgcn_s_barrier();

  for (int tt = 0; tt < 30; tt += 3) {
    STAGE(2, (tt + 2) * 32);
    COMPUTE(0);
    asm volatile("s_waitcnt vmcnt(3)" ::: "memory");
    __builtin_amdgcn_sched_barrier(0);
    __builtin_amdgcn_s_barrier();

    STAGE(0, (tt + 3) * 32);
    COMPUTE(1);
    asm volatile("s_waitcnt vmcnt(3)" ::: "memory");
    __builtin_amdgcn_sched_barrier(0);
    __builtin_amdgcn_s_barrier();

    STAGE(1, (tt + 4) * 32);
    COMPUTE(2);
    asm volatile("s_waitcnt vmcnt(3)" ::: "memory");
    __builtin_amdgcn_sched_barrier(0);
    __builtin_amdgcn_s_barrier();
  }
  COMPUTE(0);
  asm volatile("s_waitcnt vmcnt(0)" ::: "memory");
  __builtin_amdgcn_sched_barrier(0);
  __builtin_amdgcn_s_barrier();
  COMPUTE(1);
  __builtin_amdgcn_sched_barrier(0);
  __builtin_amdgcn_s_barrier();

#pragma unroll
  for (int m = 0; m < 4; ++m)
#pragma unroll
    for (int n = 0; n < 4; ++n)
#pragma unroll
      for (int rg = 0; rg < 4; ++rg) {
        const int row = wr * 64 + m * 16 + (lane >> 4) * 4 + rg;
        const int colL = wc * 64 + n * 16 + (lane & 15);
        smem[row * 132 + colL] = f32_to_bf16(acc[m][n][rg]);
      }
  __syncthreads();

  {
    const int row = tid & 255;
    const int h = tid >> 8;
    float tv[4];
    int ti_[4];
#pragma unroll
    for (int p = 0; p < 4; ++p) { tv[p] = -INFINITY; ti_[p] = 0; }
    const unsigned short* crow = smem + row * 132 + h * 64;
    const int gcol = col0 + h * 64;
    for (int j = 0; j < 64; j += 4) {
      const ushort4 c4 = *(const ushort4*)(crow + j);
      insN<4>(bf16_to_f32(c4.x), gcol + j + 0, tv, ti_);
      insN<4>(bf16_to_f32(c4.y), gcol + j + 1, tv, ti_);
      insN<4>(bf16_to_f32(c4.z), gcol + j + 2, tv, ti_);
      insN<4>(bf16_to_f32(c4.w), gcol + j + 3, tv, ti_);
    }
    const size_t base = ((size_t)(row0 + row) * NCB + cb) * TOPB + h * 4;
    *(float4*)(part_v + base) = (float4){tv[0], tv[1], tv[2], tv[3]};
    *(int4*)(part_i + base)   = (int4){ti_[0], ti_[1], ti_[2], ti_[3]};
  }
}

// ---------------------------------------------------------------------------
// FUSED K+q projection (round-22): row-space concatenation. Blocks with
// blockIdx.x < M_ROWS/256 project mem x Wk -> Kbf; the rest project
// query x Wq -> qbf. Body = round-19/20-proven proj256 pipeline.
// ---------------------------------------------------------------------------
__global__ __launch_bounds__(512, 4) void proj_kq_bf16(
    const unsigned short* __restrict__ Amem,
    const unsigned short* __restrict__ Aquery,
    const unsigned short* __restrict__ Bk,
    const unsigned short* __restrict__ Bq,
    const float* __restrict__ bk_, const float* __restrict__ bq_,
    unsigned short* __restrict__ Ck, unsigned short* __restrict__ Cq)
{
  __shared__ unsigned short smem[3 * SBUF3];

  const int tid = threadIdx.x;
  const int lane = tid & 63;
  const int wave = tid >> 6;
  const int wr = wave >> 1;
  const int wc = wave & 1;

  const bool isK = blockIdx.x < (M_ROWS / 256);
  const unsigned short* A = isK ? Amem : Aquery;
  const unsigned short* B = isK ? Bk : Bq;
  const float* bias = isK ? bk_ : bq_;
  unsigned short* C = isK ? Ck : Cq;
  const int row0 = (isK ? blockIdx.x : (blockIdx.x - M_ROWS / 256)) * 256;
  const int col0 = blockIdx.y * 128;

  const int st_r = lane >> 2;
  const int st_swz = ((lane & 3) ^ ((st_r >> 1) & 3)) * 16;

  auto STAGE = [&](int d, int k0) {
    unsigned short* buf = smem + d * SBUF3;
#pragma unroll
    for (int i = 0; i < 3; ++i) {
      const int seg = wave * 3 + i;
      if (seg < 16) {
        const int grow = row0 + seg * 16 + st_r;
        async_copy16((char*)(buf + seg * 512),
                     (const char*)(A + (size_t)grow * D_DIM + k0) + st_swz);
      } else {
        const int s2 = seg - 16;
        const int grow = col0 + s2 * 16 + st_r;
        async_copy16((char*)(buf + 8192 + s2 * 512),
                     (const char*)(B + (size_t)grow * D_DIM + k0) + st_swz);
      }
    }
  };

  f32x4 acc[4][4];
#pragma unroll
  for (int m = 0; m < 4; ++m)
#pragma unroll
    for (int n = 0; n < 4; ++n) acc[m][n] = (f32x4){0.f, 0.f, 0.f, 0.f};

  auto COMPUTE = [&](int d) {
    const unsigned short* sA = smem + d * SBUF3;
    const unsigned short* sB = sA + 8192;
    bf16x8 af[4], bfr[4];
    const int ch = lane >> 4;
#pragma unroll
    for (int m = 0; m < 4; ++m) {
      const int Ra = wr * 64 + m * 16 + (lane & 15);
      af[m] = *(const bf16x8*)((const char*)sA + Ra * 64 + ((ch ^ ((Ra >> 1) & 3)) * 16));
    }
#pragma unroll
    for (int n = 0; n < 4; ++n) {
      const int Rb = wc * 64 + n * 16 + (lane & 15);
      bfr[n] = *(const bf16x8*)((const char*)sB + Rb * 64 + ((ch ^ ((Rb >> 1) & 3)) * 16));
    }
    __builtin_amdgcn_s_setprio(1);
#pragma unroll
    for (int m = 0; m < 4; ++m)
#pragma unroll
      for (int n = 0; n < 4; ++n)
        acc[m][n] = __builtin_amdgcn_mfma_f32_16x16x32_bf16(af[m], bfr[n], acc[m][n], 0, 0, 0);
    __builtin_amdgcn_s_setprio(0);
  };

  STAGE(0, 0);
  STAGE(1, 32);
  asm volatile("s_waitcnt vmcnt(3)" ::: "memory");
  __builtin_amdgcn_sched_barrier(0);
  __builtin_amdgcn_s_barrier();

  for (int tt = 0; tt < 30; tt += 3) {
    STAGE(2, (tt + 2) * 32);
    COMPUTE(0);
    asm volatile("s_waitcnt vmcnt(3)" ::: "memory");
    __builtin_amdgcn_sched_barrier(0);
    __builtin_amdgcn_s_barrier();

    STAGE(0, (tt + 3) * 32);
    COMPUTE(1);
    asm volatile("s_waitcnt vmcnt(3)" ::: "memory");
    __builtin_amdgcn_sched_barrier(0);
    __builtin_amdgcn_s_barrier();

    STAGE(1, (tt + 4) * 32);
    COMPUTE(2);
    asm volatile("s_waitcnt vmcnt(3)" ::: "memory");
    __builtin_amdgcn_sched_barrier(0);
    __builtin_amdgcn_s_barrier();
  }
  COMPUTE(0);
  asm volatile("s_waitcnt vmcnt(0)" ::: "memory");
  __builtin_amdgcn_sched_barrier(0);
  __builtin_amdgcn_s_barrier();
  COMPUTE(1);

#pragma unroll
  for (int n = 0; n < 4; ++n) {
    const int col = col0 + wc * 64 + n * 16 + (lane & 15);
    const float bcol = bias[col];
#pragma unroll
    for (int m = 0; m < 4; ++m)
#pragma unroll
      for (int rg = 0; rg < 4; ++rg) {
        const int row = row0 + wr * 64 + m * 16 + (lane >> 4) * 4 + rg;
        C[(size_t)row * D_DIM + col] = f32_to_bf16(acc[m][n][rg] + bcol);
      }
  }
}

// ---------------------------------------------------------------------------
// Projection via bf16 MFMA (round-19/20-proven) — used for V only.
// ---------------------------------------------------------------------------
__global__ __launch_bounds__(512, 4) void proj256_bf16(
    const unsigned short* __restrict__ A,
    const unsigned short* __restrict__ B,
    const float* __restrict__ bias,
    unsigned short* __restrict__ C)
{
  __shared__ unsigned short smem[3 * SBUF3];

  const int tid = threadIdx.x;
  const int lane = tid & 63;
  const int wave = tid >> 6;
  const int wr = wave >> 1;
  const int wc = wave & 1;

  const int row0 = blockIdx.x * 256;
  const int col0 = blockIdx.y * 128;

  const int st_r = lane >> 2;
  const int st_swz = ((lane & 3) ^ ((st_r >> 1) & 3)) * 16;

  auto STAGE = [&](int d, int k0) {
    unsigned short* buf = smem + d * SBUF3;
#pragma unroll
    for (int i = 0; i < 3; ++i) {
      const int seg = wave * 3 + i;
      if (seg < 16) {
        const int grow = row0 + seg * 16 + st_r;
        async_copy16((char*)(buf + seg * 512),
                     (const char*)(A + (size_t)grow * D_DIM + k0) + st_swz);
      } else {
        const int s2 = seg - 16;
        const int grow = col0 + s2 * 16 + st_r;
        async_copy16((char*)(buf + 8192 + s2 * 512),
                     (const char*)(B + (size_t)grow * D_DIM + k0) + st_swz);
      }
    }
  };

  f32x4 acc[4][4];
#pragma unroll
  for (int m = 0; m < 4; ++m)
#pragma unroll
    for (int n = 0; n < 4; ++n) acc[m][n] = (f32x4){0.f, 0.f, 0.f, 0.f};

  auto COMPUTE = [&](int d) {
    const unsigned short* sA = smem + d * SBUF3;
    const unsigned short* sB = sA + 8192;
    bf16x8 af[4], bfr[4];
    const int ch = lane >> 4;
#pragma unroll
    for (int m = 0; m < 4; ++m) {
      const int Ra = wr * 64 + m * 16 + (lane & 15);
      af[m] = *(const bf16x8*)((const char*)sA + Ra * 64 + ((ch ^ ((Ra >> 1) & 3)) * 16));
    }
#pragma unroll
    for (int n = 0; n < 4; ++n) {
      const int Rb = wc * 64 + n * 16 + (lane & 15);
      bfr[n] = *(const bf16x8*)((const char*)sB + Rb * 64 + ((ch ^ ((Rb >> 1) & 3)) * 16));
    }
    __builtin_amdgcn_s_setprio(1);
#pragma unroll
    for (int m = 0; m < 4; ++m)
#pragma unroll
      for (int n = 0; n < 4; ++n)
        acc[m][n] = __builtin_amdgcn_mfma_f32_16x16x32_bf16(af[m], bfr[n], acc[m][n], 0, 0, 0);
    __builtin_amdgcn_s_setprio(0);
  };

  STAGE(0, 0);
  STAGE(1, 32);
  asm volatile("s_waitcnt vmcnt(3)" ::: "memory");
  __builtin_amdgcn_sched_barrier(0);
  __builtin_amdgcn_s_barrier();

  for (int tt = 0; tt < 30; tt += 3) {
    STAGE(2, (tt + 2) * 32);
    COMPUTE(0);
    asm volatile("s_waitcnt vmcnt(3)" ::: "memory");
    __builtin_amdgcn_sched_barrier(0);
    __builtin_amdgcn_s_barrier();

    STAGE(0, (tt + 3) * 32);
    COMPUTE(1);
    asm volatile("s_waitcnt vmcnt(3)" ::: "memory");
    __builtin_amdgcn_sched_barrier(0);
    __builtin_amdgcn_s_barrier();

    STAGE(1, (tt + 4) * 32);
    COMPUTE(2);
    asm volatile("s_waitcnt vmcnt(3)" ::: "memory");
    __builtin_amdgcn_sched_barrier(0);
    __builtin_amdgcn_s_barrier();
  }
  COMPUTE(0);
  asm volatile("s_waitcnt vmcnt(0)" ::: "memory");
  __builtin_amdgcn_sched_barrier(0);
  __builtin_amdgcn_s_barrier();
  COMPUTE(1);

#pragma unroll
  for (int n = 0; n < 4; ++n) {
    const int col = col0 + wc * 64 + n * 16 + (lane & 15);
    const float bcol = bias[col];
#pragma unroll
    for (int m = 0; m < 4; ++m)
#pragma unroll
      for (int rg = 0; rg < 4; ++rg) {
        const int row = row0 + wr * 64 + m * 16 + (lane >> 4) * 4 + rg;
        C[(size_t)row * D_DIM + col] = f32_to_bf16(acc[m][n][rg] + bcol);
      }
  }
}

// ---------------------------------------------------------------------------
// FUSED merge + rescore + qbk (round-22): phase 0 computes
// qbk = dot_f64(query[r], wvec) + s0 in-block; phases 1-2 = round-21-proven
// merge_rescore bodies. Kills the qbk_w pass and its launch.
// ---------------------------------------------------------------------------
__global__ __launch_bounds__(256) void merge_rescore(
    const float* __restrict__ part_v, const int* __restrict__ part_i,
    const double* __restrict__ U, const float* __restrict__ query,
    const double* __restrict__ wvec, const double* __restrict__ s0,
    const float* __restrict__ mem, int* __restrict__ topi)
{
  const int r = blockIdx.x;
  const int tid = threadIdx.x;
  const int lane = tid & 63;
  const int wave = tid >> 6;

  // ---- Phase 0: qbk (f64 dot over 256 threads x 4 elems) ----
  __shared__ double qred[4];
  __shared__ double qbs;
  {
    const float* qrow = query + (size_t)r * D_DIM + tid * 4;
    const double* wrow = wvec + tid * 4;
    double qa = 0.0;
#pragma unroll
    for (int i = 0; i < 4; ++i)
      qa = fma((double)qrow[i], wrow[i], qa);
#pragma unroll
    for (int off = 32; off > 0; off >>= 1) qa += __shfl_down(qa, off);
    if (lane == 0) qred[wave] = qa;
    __syncthreads();
    if (tid == 0) qbs = qred[0] + qred[1] + qred[2] + qred[3] + s0[0];
  }

  // ---- Phase 1: top-16 extraction (round-15-proven body) ----
  float tv[8];
  int ti[8];
  {
    const size_t base = ((size_t)r * NCB + tid) * TOPB;
    const float4 a0 = *(const float4*)(part_v + base);
    const float4 a1 = *(const float4*)(part_v + base + 4);
    const int4 b0 = *(const int4*)(part_i + base);
    const int4 b1 = *(const int4*)(part_i + base + 4);
    tv[0] = a0.x; tv[1] = a0.y; tv[2] = a0.z; tv[3] = a0.w;
    tv[4] = a1.x; tv[5] = a1.y; tv[6] = a1.z; tv[7] = a1.w;
    ti[0] = b0.x; ti[1] = b0.y; ti[2] = b0.z; ti[3] = b0.w;
    ti[4] = b1.x; ti[5] = b1.y; ti[6] = b1.z; ti[7] = b1.w;
  }
  unsigned rem = 0xFFu;

  __shared__ float wv4[4];
  __shared__ int wi4[4];
  __shared__ int winner;
  __shared__ int cand16[TOPC];

  for (int p = 0; p < TOPC; ++p) {
    float bv = -INFINITY;
    int bi = 0x7FFFFFFF;
#pragma unroll
    for (int e = 0; e < 8; ++e) {
      const bool alive = (rem >> e) & 1u;
      const float v = tv[e];
      const int ix = ti[e];
      if (alive && (v > bv || (v == bv && ix < bi))) { bv = v; bi = ix; }
    }
#pragma unroll
    for (int off = 32; off > 0; off >>= 1) {
      const float ov = __shfl_down(bv, off);
      const int oi = __shfl_down(bi, off);
      if (ov > bv || (ov == bv && oi < bi)) { bv = ov; bi = oi; }
    }
    if (lane == 0) { wv4[wave] = bv; wi4[wave] = bi; }
    __syncthreads();
    if (tid == 0) {
      float gv = wv4[0];
      int gi = wi4[0];
#pragma unroll
      for (int w = 1; w < 4; ++w)
        if (wv4[w] > gv || (wv4[w] == gv && wi4[w] < gi)) { gv = wv4[w]; gi = wi4[w]; }
      winner = gi;
      cand16[p] = gi;
    }
    __syncthreads();
    const int wgi = winner;
#pragma unroll
    for (int e = 0; e < 8; ++e)
      if (ti[e] == wgi) rem &= ~(1u << e);
  }

  // ---- Phase 2: fp64 rescore (round-16-proven body, cand + qbk from LDS) ----
  __shared__ double sval[TOPC];
  __shared__ int sidx[TOPC];

  const double* urow = U + (size_t)r * D_DIM + lane * 16;
  double uv[16];
#pragma unroll
  for (int i = 0; i < 8; ++i) {
    const double2 d2 = *(const double2*)(urow + i * 2);
    uv[i * 2] = d2.x;
    uv[i * 2 + 1] = d2.y;
  }
  const double qb = qbs;

  for (int c = wave; c < TOPC; c += 4) {
    const int ci = cand16[c];
    const float* mrow = mem + (size_t)ci * D_DIM + lane * 16;
    double acc = 0.0;
#pragma unroll
    for (int i = 0; i < 4; ++i) {
      const float4 mv = *(const float4*)(mrow + i * 4);
      acc = fma(uv[i * 4 + 0], (double)mv.x, acc);
      acc = fma(uv[i * 4 + 1], (double)mv.y, acc);
      acc = fma(uv[i * 4 + 2], (double)mv.z, acc);
      acc = fma(uv[i * 4 + 3], (double)mv.w, acc);
    }
#pragma unroll
    for (int off = 32; off > 0; off >>= 1) acc += __shfl_down(acc, off);
    if (lane == 0) { sval[c] = acc + qb; sidx[c] = ci; }
  }
  __syncthreads();

  if (tid == 0) {
    bool used[TOPC];
#pragma unroll
    for (int p = 0; p < TOPC; ++p) used[p] = false;
#pragma unroll
    for (int p = 0; p < TOPK; ++p) {
      int best = -1;
      double bv = 0.0;
      int bi = 0;
      for (int c = 0; c < TOPC; ++c) {
        if (used[c]) continue;
        const double v = sval[c];
        const int ix = sidx[c];
        if (best < 0 || v > bv || (v == bv && ix < bi)) { best = c; bv = v; bi = ix; }
      }
      used[best] = true;
      topi[(size_t)r * TOPK + p] = bi;
    }
  }
}

// ---------------------------------------------------------------------------
// Fused f32 -> bf16 cast (round-17-proven).
// ---------------------------------------------------------------------------
#define N4_MEM   (M_ROWS * D_DIM / 4)
#define N4_QUERY (B_ROWS * D_DIM / 4)
#define N4_W     (D_DIM * D_DIM / 4)
#define N4_TOTAL (N4_MEM + N4_QUERY + 3 * N4_W)

__global__ __launch_bounds__(256) void cast_all_bf16(
    const float* __restrict__ mem, const float* __restrict__ query,
    const float* __restrict__ Wk, const float* __restrict__ Wv,
    const float* __restrict__ Wq,
    unsigned short* __restrict__ membf, unsigned short* __restrict__ querybf,
    unsigned short* __restrict__ wkbf, unsigned short* __restrict__ wvbf,
    unsigned short* __restrict__ wqbf)
{
  int i = blockIdx.x * 256 + threadIdx.x;
  if (i >= N4_TOTAL) return;
  const float* src;
  unsigned short* dst;
  if (i < N4_MEM) { src = mem; dst = membf; }
  else if ((i -= N4_MEM) < N4_QUERY) { src = query; dst = querybf; }
  else if ((i -= N4_QUERY) < N4_W) { src = Wk; dst = wkbf; }
  else if ((i -= N4_W) < N4_W) { src = Wv; dst = wvbf; }
  else { i -= N4_W; src = Wq; dst = wqbf; }
  const float4 v = *(const float4*)(src + (size_t)i * 4);
  ushort4 o;
  o.x = f32_to_bf16(v.x);
  o.y = f32_to_bf16(v.y);
  o.z = f32_to_bf16(v.z);
  o.w = f32_to_bf16(v.w);
  *(ushort4*)(dst + (size_t)i * 4) = o;
}

// ---------------------------------------------------------------------------
// Gather selected V rows (bf16) + LayerNorm in f32 (round-18-proven).
// ---------------------------------------------------------------------------
__global__ __launch_bounds__(256) void gather_ln(
    const unsigned short* __restrict__ V, const int* __restrict__ topi,
    const float* __restrict__ gamma, const float* __restrict__ beta,
    float* __restrict__ out)
{
  const int row = blockIdx.x;
  const int tid = threadIdx.x;
  const int idx = topi[row];
  const unsigned short* src = V + (size_t)idx * D_DIM;
  const ushort4 raw = *(const ushort4*)(src + tid * 4);
  const float v0 = bf16_to_f32(raw.x);
  const float v1 = bf16_to_f32(raw.y);
  const float v2 = bf16_to_f32(raw.z);
  const float v3 = bf16_to_f32(raw.w);
  float s = v0 + v1 + v2 + v3;
  float s2 = v0 * v0 + v1 * v1 + v2 * v2 + v3 * v3;
#pragma unroll
  for (int off = 32; off > 0; off >>= 1) {
    s += __shfl_down(s, off);
    s2 += __shfl_down(s2, off);
  }
  __shared__ float red[8];
  __shared__ float stats[2];
  const int wid = tid >> 6;
  if ((tid & 63) == 0) { red[wid] = s; red[4 + wid] = s2; }
  __syncthreads();
  if (tid == 0) {
    const float S = red[0] + red[1] + red[2] + red[3];
    const float S2 = red[4] + red[5] + red[6] + red[7];
    const float mu = S * (1.0f / D_DIM);
    const float var = S2 * (1.0f / D_DIM) - mu * mu;
    stats[0] = mu;
    stats[1] = rsqrtf(var + 1e-5f);
  }
  __syncthreads();
  const float mu = stats[0], rstd = stats[1];
  const float4 g4 = *(const float4*)(gamma + tid * 4);
  const float4 b4 = *(const float4*)(beta + tid * 4);
  float4 o;
  o.x = (v0 - mu) * rstd * g4.x + b4.x;
  o.y = (v1 - mu) * rstd * g4.y + b4.y;
  o.z = (v2 - mu) * rstd * g4.z + b4.z;
  o.w = (v3 - mu) * rstd * g4.w + b4.w;
  *(float4*)(out + (size_t)row * D_DIM + tid * 4) = o;
}

extern "C" void kernel_launch(void* const* d_in, const int* in_sizes, int n_in,
                              void* d_out, int out_size, void* d_ws, size_t ws_size,
                              hipStream_t stream)
{
  const float* query = (const float*)d_in[0];
  const float* mem   = (const float*)d_in[1];
  const float* Wq    = (const float*)d_in[2];
  const float* bq    = (const float*)d_in[3];
  const float* Wk    = (const float*)d_in[4];
  const float* bk    = (const float*)d_in[5];
  const float* Wv    = (const float*)d_in[6];
  const float* bv    = (const float*)d_in[7];
  const float* gamma = (const float*)d_in[8];
  const float* beta  = (const float*)d_in[9];
  float* out = (float*)d_out;

  char* ws = (char*)d_ws;
  double* u64 = (double*)ws;   ws += (size_t)B_ROWS * D_DIM * sizeof(double);
  double* G = (double*)ws;     ws += (size_t)D_DIM * D_DIM * sizeof(double);
  unsigned short* qbf = (unsigned short*)ws;
  ws += (size_t)B_ROWS * D_DIM * sizeof(unsigned short);
  unsigned short* querybf = (unsigned short*)ws;
  ws += (size_t)B_ROWS * D_DIM * sizeof(unsigned short);
  unsigned short* membf = (unsigned short*)ws;
  ws += (size_t)M_ROWS * D_DIM * sizeof(unsigned short);
  char* Aregion = ws;
  ws += (size_t)M_ROWS * D_DIM * sizeof(unsigned short)
      + 2 * (size_t)B_ROWS * NCB * TOPB * sizeof(float);
  double* wvec = (double*)ws;  ws += (size_t)D_DIM * sizeof(double);
  double* ubias = (double*)ws; ws += (size_t)D_DIM * sizeof(double);
  double* s0 = (double*)ws;    ws += 2 * sizeof(double);
  int* topi = (int*)ws;

  unsigned short* Kbf = (unsigned short*)Aregion;
  float* part_v = (float*)(Aregion + (size_t)M_ROWS * D_DIM * sizeof(unsigned short));
  int* part_i = (int*)((char*)part_v + (size_t)B_ROWS * NCB * TOPB * sizeof(float));
  unsigned short* wkbf = (unsigned short*)G;
  unsigned short* wvbf = wkbf + (size_t)D_DIM * D_DIM;
  unsigned short* wqbf = wvbf + (size_t)D_DIM * D_DIM;
  unsigned short* Vbf = (unsigned short*)Aregion;

  // Selection chain (f64): G = Wq^T@Wk (+bias terms fused); u = query@G + bq@Wk.
  gram_bias<<<dim3(265), 256, 0, stream>>>(Wq, Wk, bq, bk, G, wvec, ubias, s0);
  uproj_G<<<dim3(B_ROWS / 64, D_DIM / 64), 256, 0, stream>>>(query, G, ubias, u64);

  // Candidate chain (bf16): fused casts; G dead -> W casts overlay it.
  cast_all_bf16<<<dim3((N4_TOTAL + 255) / 256), 256, 0, stream>>>(
      mem, query, Wk, Wv, Wq, membf, querybf, wkbf, wvbf, wqbf);

  proj_kq_bf16<<<dim3((M_ROWS + B_ROWS) / 256, D_DIM / 128), 512, 0, stream>>>(
      membf, querybf, wkbf, wqbf, bk, bq, Kbf, qbf);

  sims_topc_gemm<<<dim3((B_ROWS / 256) * NCB), 512, 0, stream>>>(qbf, Kbf, part_v, part_i);
  merge_rescore<<<dim3(B_ROWS), 256, 0, stream>>>(part_v, part_i, u64, query, wvec, s0, mem, topi);

  // V path (bf16 out, overlays dead Kbf/parts region).
  proj256_bf16<<<dim3(M_ROWS / 256, D_DIM / 128), 512, 0, stream>>>(membf, wvbf, bv, Vbf);
  gather_ln<<<dim3(B_ROWS * TOPK), 256, 0, stream>>>(Vbf, topi, gamma, beta, out);
}

// Round 23
// 1052.187 us; speedup vs baseline: 7.6128x; 1.0527x over previous
//
#include <hip/hip_runtime.h>
#include <hip/hip_bf16.h>
#include <math.h>

#define D_DIM 1024
#define B_ROWS 4096
#define M_ROWS 32768
#define TOPK 8
#define TOPC 16
#define TOPB 8
#define NCB (M_ROWS / 128)

typedef __attribute__((ext_vector_type(8))) short bf16x8;
typedef __attribute__((ext_vector_type(4))) float f32x4;

__device__ __forceinline__ unsigned short f32_to_bf16(float f) {
  unsigned int u = __float_as_uint(f);
  unsigned int r = (u + 0x7FFFu + ((u >> 16) & 1u)) >> 16;
  return (unsigned short)r;
}
__device__ __forceinline__ float bf16_to_f32(unsigned short h) {
  return __uint_as_float(((unsigned int)h) << 16);
}
__device__ __forceinline__ void async_copy16(void* lds, const void* g) {
  __builtin_amdgcn_global_load_lds(
      (const __attribute__((address_space(1))) unsigned int*)g,
      (__attribute__((address_space(3))) unsigned int*)lds, 16, 0, 0);
}

template <int N>
__device__ __forceinline__ void insN(float v, int idx,
                                     float* __restrict__ tv,
                                     int* __restrict__ ti) {
  if (v < tv[N - 1]) return;
  if (v == tv[N - 1] && idx > ti[N - 1]) return;
  float cv = v;
  int ci = idx;
#pragma unroll
  for (int p = 0; p < N; ++p) {
    if (cv > tv[p] || (cv == tv[p] && ci < ti[p])) {
      const float t0 = tv[p]; tv[p] = cv; cv = t0;
      const int t1 = ti[p]; ti[p] = ci; ci = t1;
    }
  }
}

#define N4_MEM   (M_ROWS * D_DIM / 4)
#define N4_QUERY (B_ROWS * D_DIM / 4)
#define N4_W     (D_DIM * D_DIM / 4)
#define N4_TOTAL (N4_MEM + N4_QUERY + 3 * N4_W)
#define NCAST_BLK ((N4_TOTAL + 255) / 256)

// ---------------------------------------------------------------------------
// FUSED gram + bias terms + casts (round-23). Blocks 0-255: G tile
// (round-21-proven dbuf body). Blocks 256-259: wvec; 260-263: ubias; 264: s0.
// Blocks >= 265: f32->bf16 casts (round-17-proven body) — fills the CUs that
// gram leaves idle (265-block gram ~ 1 block/CU). Casts now write a DEDICATED
// region (no longer overlaying G, which gram writes concurrently).
// ---------------------------------------------------------------------------
__global__ __launch_bounds__(256) void gram_bias_cast(
    const float* __restrict__ Wq, const float* __restrict__ Wk,
    const float* __restrict__ bq, const float* __restrict__ bk,
    const float* __restrict__ mem, const float* __restrict__ query,
    const float* __restrict__ Wv,
    double* __restrict__ G, double* __restrict__ wvec,
    double* __restrict__ ubias, double* __restrict__ s0,
    unsigned short* __restrict__ membf, unsigned short* __restrict__ querybf,
    unsigned short* __restrict__ wkbf, unsigned short* __restrict__ wvbf,
    unsigned short* __restrict__ wqbf)
{
  __shared__ float sA[2][32][68];
  __shared__ float sB[2][32][68];
  const int blk = blockIdx.x;
  const int tid = threadIdx.x;

  if (blk < 256) {
    const int tx = tid & 15, ty = tid >> 4;
    const int f0 = (blk >> 4) * 64;
    const int e0 = (blk & 15) * 64;

    double acc[4][4];
#pragma unroll
    for (int i = 0; i < 4; ++i)
#pragma unroll
      for (int j = 0; j < 4; ++j) acc[i][j] = 0.0;

    auto STAGE = [&](int d, int k0) {
#pragma unroll
      for (int it = 0; it < 2; ++it) {
        const int L = it * 256 + tid;
        const int kk = L >> 4, c4 = (L & 15) * 4;
        *(float4*)&sA[d][kk][c4] = *(const float4*)(Wq + (size_t)(k0 + kk) * D_DIM + f0 + c4);
        *(float4*)&sB[d][kk][c4] = *(const float4*)(Wk + (size_t)(k0 + kk) * D_DIM + e0 + c4);
      }
    };

    STAGE(0, 0);
    __syncthreads();
    int cur = 0;
    for (int t = 0; t < 32; ++t) {
      if (t < 31) STAGE(cur ^ 1, (t + 1) * 32);
#pragma unroll
      for (int kk = 0; kk < 32; ++kk) {
        const double a[4] = {sA[cur][kk][ty * 4 + 0], sA[cur][kk][ty * 4 + 1],
                             sA[cur][kk][ty * 4 + 2], sA[cur][kk][ty * 4 + 3]};
        const double b[4] = {sB[cur][kk][tx * 4 + 0], sB[cur][kk][tx * 4 + 1],
                             sB[cur][kk][tx * 4 + 2], sB[cur][kk][tx * 4 + 3]};
#pragma unroll
        for (int i = 0; i < 4; ++i)
#pragma unroll
          for (int j = 0; j < 4; ++j)
            acc[i][j] = fma(a[i], b[j], acc[i][j]);
      }
      __syncthreads();
      cur ^= 1;
    }
#pragma unroll
    for (int i = 0; i < 4; ++i)
#pragma unroll
      for (int j = 0; j < 4; ++j)
        G[(size_t)(f0 + ty * 4 + i) * D_DIM + e0 + tx * 4 + j] = acc[i][j];
  } else if (blk < 260) {
    const int c = (blk - 256) * 256 + tid;
    double acc = 0.0;
    for (int n = 0; n < D_DIM; ++n)
      acc = fma((double)Wq[(size_t)n * D_DIM + c], (double)bk[n], acc);
    wvec[c] = acc;
  } else if (blk < 264) {
    const int c = (blk - 260) * 256 + tid;
    double acc = 0.0;
    for (int n = 0; n < D_DIM; ++n)
      acc = fma((double)Wk[(size_t)n * D_DIM + c], (double)bq[n], acc);
    ubias[c] = acc;
  } else if (blk == 264) {
    double acc = 0.0;
#pragma unroll
    for (int i = 0; i < 4; ++i) {
      const int idx = tid * 4 + i;
      acc = fma((double)bq[idx], (double)bk[idx], acc);
    }
#pragma unroll
    for (int off = 32; off > 0; off >>= 1) acc += __shfl_down(acc, off);
    __shared__ double red[4];
    if ((tid & 63) == 0) red[tid >> 6] = acc;
    __syncthreads();
    if (tid == 0) s0[0] = red[0] + red[1] + red[2] + red[3];
  } else {
    int i = (blk - 265) * 256 + tid;
    if (i >= N4_TOTAL) return;
    const float* src;
    unsigned short* dst;
    if (i < N4_MEM) { src = mem; dst = membf; }
    else if ((i -= N4_MEM) < N4_QUERY) { src = query; dst = querybf; }
    else if ((i -= N4_QUERY) < N4_W) { src = Wk; dst = wkbf; }
    else if ((i -= N4_W) < N4_W) { src = Wv; dst = wvbf; }
    else { i -= N4_W; src = Wq; dst = wqbf; }
    const float4 v = *(const float4*)(src + (size_t)i * 4);
    ushort4 o;
    o.x = f32_to_bf16(v.x);
    o.y = f32_to_bf16(v.y);
    o.z = f32_to_bf16(v.z);
    o.w = f32_to_bf16(v.w);
    *(ushort4*)(dst + (size_t)i * 4) = o;
  }
}

// ---------------------------------------------------------------------------
// u[b,d] = sum_e query[b,e]*G[e,d] + ubias[d], f64 (round-20/21-proven dbuf).
// ---------------------------------------------------------------------------
__global__ __launch_bounds__(256) void uproj_G(
    const float* __restrict__ query, const double* __restrict__ G,
    const double* __restrict__ ubias, double* __restrict__ U)
{
  __shared__ double sAdT[2][32][66];
  __shared__ double sBd[2][32][68];
  const int tid = threadIdx.x;
  const int tx = tid & 15, ty = tid >> 4;
  const int row0 = blockIdx.x * 64;
  const int col0 = blockIdx.y * 64;

  double acc[4][4];
#pragma unroll
  for (int i = 0; i < 4; ++i)
#pragma unroll
    for (int j = 0; j < 4; ++j) acc[i][j] = 0.0;

  auto STAGE = [&](int d, int k0) {
#pragma unroll
    for (int it = 0; it < 2; ++it) {
      const int L = it * 256 + tid;
      const int rowa = L >> 3, c4 = (L & 7) * 4;
      const float4 v =
          *(const float4*)(query + (size_t)(row0 + rowa) * D_DIM + k0 + c4);
      sAdT[d][c4 + 0][rowa] = (double)v.x;
      sAdT[d][c4 + 1][rowa] = (double)v.y;
      sAdT[d][c4 + 2][rowa] = (double)v.z;
      sAdT[d][c4 + 3][rowa] = (double)v.w;
    }
#pragma unroll
    for (int it = 0; it < 4; ++it) {
      const int L = it * 256 + tid;
      const int kk = L >> 5, c2 = (L & 31) * 2;
      *(double2*)&sBd[d][kk][c2] =
          *(const double2*)(G + (size_t)(k0 + kk) * D_DIM + col0 + c2);
    }
  };

  STAGE(0, 0);
  __syncthreads();
  int cur = 0;
  for (int t = 0; t < 32; ++t) {
    if (t < 31) STAGE(cur ^ 1, (t + 1) * 32);
#pragma unroll
    for (int kk = 0; kk < 32; ++kk) {
      const double2 p0 = *(const double2*)&sAdT[cur][kk][ty * 4];
      const double2 p1 = *(const double2*)&sAdT[cur][kk][ty * 4 + 2];
      const double a[4] = {p0.x, p0.y, p1.x, p1.y};
      const double bb[4] = {sBd[cur][kk][tx * 4 + 0], sBd[cur][kk][tx * 4 + 1],
                            sBd[cur][kk][tx * 4 + 2], sBd[cur][kk][tx * 4 + 3]};
#pragma unroll
      for (int i = 0; i < 4; ++i)
#pragma unroll
        for (int j = 0; j < 4; ++j)
          acc[i][j] = fma(a[i], bb[j], acc[i][j]);
    }
    __syncthreads();
    cur ^= 1;
  }
  const double ub[4] = {ubias[col0 + tx * 4 + 0], ubias[col0 + tx * 4 + 1],
                        ubias[col0 + tx * 4 + 2], ubias[col0 + tx * 4 + 3]};
#pragma unroll
  for (int i = 0; i < 4; ++i) {
    const size_t base = (size_t)(row0 + ty * 4 + i) * D_DIM + col0 + tx * 4;
    *(double2*)(U + base)     = (double2){acc[i][0] + ub[0], acc[i][1] + ub[1]};
    *(double2*)(U + base + 2) = (double2){acc[i][2] + ub[2], acc[i][3] + ub[3]};
  }
}

// ---------------------------------------------------------------------------
// Fused sims + per-half top-4 (rounds 18-22 proven).
// ---------------------------------------------------------------------------
#define SBUF3 12288
__global__ __launch_bounds__(512, 4) void sims_topc_gemm(
    const unsigned short* __restrict__ A, const unsigned short* __restrict__ B,
    float* __restrict__ part_v, int* __restrict__ part_i)
{
  __shared__ unsigned short smem[3 * SBUF3];

  const int tid = threadIdx.x;
  const int lane = tid & 63;
  const int wave = tid >> 6;
  const int wr = wave >> 1;
  const int wc = wave & 1;

  const int bid = blockIdx.x;
  const int x = bid & 7;
  const int t9 = bid >> 3;
  const int cbg = t9 >> 7;
  const int r = (t9 >> 3) & 15;
  const int cbl = t9 & 7;
  const int cb = (x * 4 + cbg) * 8 + cbl;
  const int row0 = r * 256;
  const int col0 = cb * 128;

  const int st_r = lane >> 2;
  const int st_swz = ((lane & 3) ^ ((st_r >> 1) & 3)) * 16;

  auto STAGE = [&](int d, int k0) {
    unsigned short* buf = smem + d * SBUF3;
#pragma unroll
    for (int i = 0; i < 3; ++i) {
      const int seg = wave * 3 + i;
      if (seg < 16) {
        const int grow = row0 + seg * 16 + st_r;
        async_copy16((char*)(buf + seg * 512),
                     (const char*)(A + (size_t)grow * D_DIM + k0) + st_swz);
      } else {
        const int s2 = seg - 16;
        const int grow = col0 + s2 * 16 + st_r;
        async_copy16((char*)(buf + 8192 + s2 * 512),
                     (const char*)(B + (size_t)grow * D_DIM + k0) + st_swz);
      }
    }
  };

  f32x4 acc[4][4];
#pragma unroll
  for (int m = 0; m < 4; ++m)
#pragma unroll
    for (int n = 0; n < 4; ++n) acc[m][n] = (f32x4){0.f, 0.f, 0.f, 0.f};

  auto COMPUTE = [&](int d) {
    const unsigned short* sA = smem + d * SBUF3;
    const unsigned short* sB = sA + 8192;
    bf16x8 af[4], bfr[4];
    const int ch = lane >> 4;
#pragma unroll
    for (int m = 0; m < 4; ++m) {
      const int Ra = wr * 64 + m * 16 + (lane & 15);
      af[m] = *(const bf16x8*)((const char*)sA + Ra * 64 + ((ch ^ ((Ra >> 1) & 3)) * 16));
    }
#pragma unroll
    for (int n = 0; n < 4; ++n) {
      const int Rb = wc * 64 + n * 16 + (lane & 15);
      bfr[n] = *(const bf16x8*)((const char*)sB + Rb * 64 + ((ch ^ ((Rb >> 1) & 3)) * 16));
    }
    __builtin_amdgcn_s_setprio(1);
#pragma unroll
    for (int m = 0; m < 4; ++m)
#pragma unroll
      for (int n = 0; n < 4; ++n)
        acc[m][n] = __builtin_amdgcn_mfma_f32_16x16x32_bf16(af[m], bfr[n], acc[m][n], 0, 0, 0);
    __builtin_amdgcn_s_setprio(0);
  };

  STAGE(0, 0);
  STAGE(1, 32);
  asm volatile("s_waitcnt vmcnt(3)" ::: "memory");
  __builtin_amdgcn_sched_barrier(0);
  __builtin_amdgcn_s_barrier();

  for (int tt = 0; tt < 30; tt += 3) {
    STAGE(2, (tt + 2) * 32);
    COMPUTE(0);
    asm volatile("s_waitcnt vmcnt(3)" ::: "memory");
    __builtin_amdgcn_sched_barrier(0);
    __builtin_amdgcn_s_barrier();

    STAGE(0, (tt + 3) * 32);
    COMPUTE(1);
    asm volatile("s_waitcnt vmcnt(3)" ::: "memory");
    __builtin_amdgcn_sched_barrier(0);
    __builtin_amdgcn_s_barrier();

    STAGE(1, (tt + 4) * 32);
    COMPUTE(2);
    asm volatile("s_waitcnt vmcnt(3)" ::: "memory");
    __builtin_amdgcn_sched_barrier(0);
    __builtin_amdgcn_s_barrier();
  }
  COMPUTE(0);
  asm volatile("s_waitcnt vmcnt(0)" ::: "memory");
  __builtin_amdgcn_sched_barrier(0);
  __builtin_amdgcn_s_barrier();
  COMPUTE(1);
  __builtin_amdgcn_sched_barrier(0);
  __builtin_amdgcn_s_barrier();

#pragma unroll
  for (int m = 0; m < 4; ++m)
#pragma unroll
    for (int n = 0; n < 4; ++n)
#pragma unroll
      for (int rg = 0; rg < 4; ++rg) {
        const int row = wr * 64 + m * 16 + (lane >> 4) * 4 + rg;
        const int colL = wc * 64 + n * 16 + (lane & 15);
        smem[row * 132 + colL] = f32_to_bf16(acc[m][n][rg]);
      }
  __syncthreads();

  {
    const int row = tid & 255;
    const int h = tid >> 8;
    float tv[4];
    int ti_[4];
#pragma unroll
    for (int p = 0; p < 4; ++p) { tv[p] = -INFINITY; ti_[p] = 0; }
    const unsigned short* crow = smem + row * 132 + h * 64;
    const int gcol = col0 + h * 64;
    for (int j = 0; j < 64; j += 4) {
      const ushort4 c4 = *(const ushort4*)(crow + j);
      insN<4>(bf16_to_f32(c4.x), gcol + j + 0, tv, ti_);
      insN<4>(bf16_to_f32(c4.y), gcol + j + 1, tv, ti_);
      insN<4>(bf16_to_f32(c4.z), gcol + j + 2, tv, ti_);
      insN<4>(bf16_to_f32(c4.w), gcol + j + 3, tv, ti_);
    }
    const size_t base = ((size_t)(row0 + row) * NCB + cb) * TOPB + h * 4;
    *(float4*)(part_v + base) = (float4){tv[0], tv[1], tv[2], tv[3]};
    *(int4*)(part_i + base)   = (int4){ti_[0], ti_[1], ti_[2], ti_[3]};
  }
}

// ---------------------------------------------------------------------------
// FUSED K+q projection (round-22-proven).
// ---------------------------------------------------------------------------
__global__ __launch_bounds__(512, 4) void proj_kq_bf16(
    const unsigned short* __restrict__ Amem,
    const unsigned short* __restrict__ Aquery,
    const unsigned short* __restrict__ Bk,
    const unsigned short* __restrict__ Bq,
    const float* __restrict__ bk_, const float* __restrict__ bq_,
    unsigned short* __restrict__ Ck, unsigned short* __restrict__ Cq)
{
  __shared__ unsigned short smem[3 * SBUF3];

  const int tid = threadIdx.x;
  const int lane = tid & 63;
  const int wave = tid >> 6;
  const int wr = wave >> 1;
  const int wc = wave & 1;

  const bool isK = blockIdx.x < (M_ROWS / 256);
  const unsigned short* A = isK ? Amem : Aquery;
  const unsigned short* B = isK ? Bk : Bq;
  const float* bias = isK ? bk_ : bq_;
  unsigned short* C = isK ? Ck : Cq;
  const int row0 = (isK ? blockIdx.x : (blockIdx.x - M_ROWS / 256)) * 256;
  const int col0 = blockIdx.y * 128;

  const int st_r = lane >> 2;
  const int st_swz = ((lane & 3) ^ ((st_r >> 1) & 3)) * 16;

  auto STAGE = [&](int d, int k0) {
    unsigned short* buf = smem + d * SBUF3;
#pragma unroll
    for (int i = 0; i < 3; ++i) {
      const int seg = wave * 3 + i;
      if (seg < 16) {
        const int grow = row0 + seg * 16 + st_r;
        async_copy16((char*)(buf + seg * 512),
                     (const char*)(A + (size_t)grow * D_DIM + k0) + st_swz);
      } else {
        const int s2 = seg - 16;
        const int grow = col0 + s2 * 16 + st_r;
        async_copy16((char*)(buf + 8192 + s2 * 512),
                     (const char*)(B + (size_t)grow * D_DIM + k0) + st_swz);
      }
    }
  };

  f32x4 acc[4][4];
#pragma unroll
  for (int m = 0; m < 4; ++m)
#pragma unroll
    for (int n = 0; n < 4; ++n) acc[m][n] = (f32x4){0.f, 0.f, 0.f, 0.f};

  auto COMPUTE = [&](int d) {
    const unsigned short* sA = smem + d * SBUF3;
    const unsigned short* sB = sA + 8192;
    bf16x8 af[4], bfr[4];
    const int ch = lane >> 4;
#pragma unroll
    for (int m = 0; m < 4; ++m) {
      const int Ra = wr * 64 + m * 16 + (lane & 15);
      af[m] = *(const bf16x8*)((const char*)sA + Ra * 64 + ((ch ^ ((Ra >> 1) & 3)) * 16));
    }
#pragma unroll
    for (int n = 0; n < 4; ++n) {
      const int Rb = wc * 64 + n * 16 + (lane & 15);
      bfr[n] = *(const bf16x8*)((const char*)sB + Rb * 64 + ((ch ^ ((Rb >> 1) & 3)) * 16));
    }
    __builtin_amdgcn_s_setprio(1);
#pragma unroll
    for (int m = 0; m < 4; ++m)
#pragma unroll
      for (int n = 0; n < 4; ++n)
        acc[m][n] = __builtin_amdgcn_mfma_f32_16x16x32_bf16(af[m], bfr[n], acc[m][n], 0, 0, 0);
    __builtin_amdgcn_s_setprio(0);
  };

  STAGE(0, 0);
  STAGE(1, 32);
  asm volatile("s_waitcnt vmcnt(3)" ::: "memory");
  __builtin_amdgcn_sched_barrier(0);
  __builtin_amdgcn_s_barrier();

  for (int tt = 0; tt < 30; tt += 3) {
    STAGE(2, (tt + 2) * 32);
    COMPUTE(0);
    asm volatile("s_waitcnt vmcnt(3)" ::: "memory");
    __builtin_amdgcn_sched_barrier(0);
    __builtin_amdgcn_s_barrier();

    STAGE(0, (tt + 3) * 32);
    COMPUTE(1);
    asm volatile("s_waitcnt vmcnt(3)" ::: "memory");
    __builtin_amdgcn_sched_barrier(0);
    __builtin_amdgcn_s_barrier();

    STAGE(1, (tt + 4) * 32);
    COMPUTE(2);
    asm volatile("s_waitcnt vmcnt(3)" ::: "memory");
    __builtin_amdgcn_sched_barrier(0);
    __builtin_amdgcn_s_barrier();
  }
  COMPUTE(0);
  asm volatile("s_waitcnt vmcnt(0)" ::: "memory");
  __builtin_amdgcn_sched_barrier(0);
  __builtin_amdgcn_s_barrier();
  COMPUTE(1);

#pragma unroll
  for (int n = 0; n < 4; ++n) {
    const int col = col0 + wc * 64 + n * 16 + (lane & 15);
    const float bcol = bias[col];
#pragma unroll
    for (int m = 0; m < 4; ++m)
#pragma unroll
      for (int rg = 0; rg < 4; ++rg) {
        const int row = row0 + wr * 64 + m * 16 + (lane >> 4) * 4 + rg;
        C[(size_t)row * D_DIM + col] = f32_to_bf16(acc[m][n][rg] + bcol);
      }
  }
}

// ---------------------------------------------------------------------------
// Projection via bf16 MFMA (round-19/20-proven) — used for V only.
// ---------------------------------------------------------------------------
__global__ __launch_bounds__(512, 4) void proj256_bf16(
    const unsigned short* __restrict__ A,
    const unsigned short* __restrict__ B,
    const float* __restrict__ bias,
    unsigned short* __restrict__ C)
{
  __shared__ unsigned short smem[3 * SBUF3];

  const int tid = threadIdx.x;
  const int lane = tid & 63;
  const int wave = tid >> 6;
  const int wr = wave >> 1;
  const int wc = wave & 1;

  const int row0 = blockIdx.x * 256;
  const int col0 = blockIdx.y * 128;

  const int st_r = lane >> 2;
  const int st_swz = ((lane & 3) ^ ((st_r >> 1) & 3)) * 16;

  auto STAGE = [&](int d, int k0) {
    unsigned short* buf = smem + d * SBUF3;
#pragma unroll
    for (int i = 0; i < 3; ++i) {
      const int seg = wave * 3 + i;
      if (seg < 16) {
        const int grow = row0 + seg * 16 + st_r;
        async_copy16((char*)(buf + seg * 512),
                     (const char*)(A + (size_t)grow * D_DIM + k0) + st_swz);
      } else {
        const int s2 = seg - 16;
        const int grow = col0 + s2 * 16 + st_r;
        async_copy16((char*)(buf + 8192 + s2 * 512),
                     (const char*)(B + (size_t)grow * D_DIM + k0) + st_swz);
      }
    }
  };

  f32x4 acc[4][4];
#pragma unroll
  for (int m = 0; m < 4; ++m)
#pragma unroll
    for (int n = 0; n < 4; ++n) acc[m][n] = (f32x4){0.f, 0.f, 0.f, 0.f};

  auto COMPUTE = [&](int d) {
    const unsigned short* sA = smem + d * SBUF3;
    const unsigned short* sB = sA + 8192;
    bf16x8 af[4], bfr[4];
    const int ch = lane >> 4;
#pragma unroll
    for (int m = 0; m < 4; ++m) {
      const int Ra = wr * 64 + m * 16 + (lane & 15);
      af[m] = *(const bf16x8*)((const char*)sA + Ra * 64 + ((ch ^ ((Ra >> 1) & 3)) * 16));
    }
#pragma unroll
    for (int n = 0; n < 4; ++n) {
      const int Rb = wc * 64 + n * 16 + (lane & 15);
      bfr[n] = *(const bf16x8*)((const char*)sB + Rb * 64 + ((ch ^ ((Rb >> 1) & 3)) * 16));
    }
    __builtin_amdgcn_s_setprio(1);
#pragma unroll
    for (int m = 0; m < 4; ++m)
#pragma unroll
      for (int n = 0; n < 4; ++n)
        acc[m][n] = __builtin_amdgcn_mfma_f32_16x16x32_bf16(af[m], bfr[n], acc[m][n], 0, 0, 0);
    __builtin_amdgcn_s_setprio(0);
  };

  STAGE(0, 0);
  STAGE(1, 32);
  asm volatile("s_waitcnt vmcnt(3)" ::: "memory");
  __builtin_amdgcn_sched_barrier(0);
  __builtin_amdgcn_s_barrier();

  for (int tt = 0; tt < 30; tt += 3) {
    STAGE(2, (tt + 2) * 32);
    COMPUTE(0);
    asm volatile("s_waitcnt vmcnt(3)" ::: "memory");
    __builtin_amdgcn_sched_barrier(0);
    __builtin_amdgcn_s_barrier();

    STAGE(0, (tt + 3) * 32);
    COMPUTE(1);
    asm volatile("s_waitcnt vmcnt(3)" ::: "memory");
    __builtin_amdgcn_sched_barrier(0);
    __builtin_amdgcn_s_barrier();

    STAGE(1, (tt + 4) * 32);
    COMPUTE(2);
    asm volatile("s_waitcnt vmcnt(3)" ::: "memory");
    __builtin_amdgcn_sched_barrier(0);
    __builtin_amdgcn_s_barrier();
  }
  COMPUTE(0);
  asm volatile("s_waitcnt vmcnt(0)" ::: "memory");
  __builtin_amdgcn_sched_barrier(0);
  __builtin_amdgcn_s_barrier();
  COMPUTE(1);

#pragma unroll
  for (int n = 0; n < 4; ++n) {
    const int col = col0 + wc * 64 + n * 16 + (lane & 15);
    const float bcol = bias[col];
#pragma unroll
    for (int m = 0; m < 4; ++m)
#pragma unroll
      for (int rg = 0; rg < 4; ++rg) {
        const int row = row0 + wr * 64 + m * 16 + (lane >> 4) * 4 + rg;
        C[(size_t)row * D_DIM + col] = f32_to_bf16(acc[m][n][rg] + bcol);
      }
  }
}

// ---------------------------------------------------------------------------
// FUSED merge + rescore + qbk (round-22-proven).
// ---------------------------------------------------------------------------
__global__ __launch_bounds__(256) void merge_rescore(
    const float* __restrict__ part_v, const int* __restrict__ part_i,
    const double* __restrict__ U, const float* __restrict__ query,
    const double* __restrict__ wvec, const double* __restrict__ s0,
    const float* __restrict__ mem, int* __restrict__ topi)
{
  const int r = blockIdx.x;
  const int tid = threadIdx.x;
  const int lane = tid & 63;
  const int wave = tid >> 6;

  __shared__ double qred[4];
  __shared__ double qbs;
  {
    const float* qrow = query + (size_t)r * D_DIM + tid * 4;
    const double* wrow = wvec + tid * 4;
    double qa = 0.0;
#pragma unroll
    for (int i = 0; i < 4; ++i)
      qa = fma((double)qrow[i], wrow[i], qa);
#pragma unroll
    for (int off = 32; off > 0; off >>= 1) qa += __shfl_down(qa, off);
    if (lane == 0) qred[wave] = qa;
    __syncthreads();
    if (tid == 0) qbs = qred[0] + qred[1] + qred[2] + qred[3] + s0[0];
  }

  float tv[8];
  int ti[8];
  {
    const size_t base = ((size_t)r * NCB + tid) * TOPB;
    const float4 a0 = *(const float4*)(part_v + base);
    const float4 a1 = *(const float4*)(part_v + base + 4);
    const int4 b0 = *(const int4*)(part_i + base);
    const int4 b1 = *(const int4*)(part_i + base + 4);
    tv[0] = a0.x; tv[1] = a0.y; tv[2] = a0.z; tv[3] = a0.w;
    tv[4] = a1.x; tv[5] = a1.y; tv[6] = a1.z; tv[7] = a1.w;
    ti[0] = b0.x; ti[1] = b0.y; ti[2] = b0.z; ti[3] = b0.w;
    ti[4] = b1.x; ti[5] = b1.y; ti[6] = b1.z; ti[7] = b1.w;
  }
  unsigned rem = 0xFFu;

  __shared__ float wv4[4];
  __shared__ int wi4[4];
  __shared__ int winner;
  __shared__ int cand16[TOPC];

  for (int p = 0; p < TOPC; ++p) {
    float bv = -INFINITY;
    int bi = 0x7FFFFFFF;
#pragma unroll
    for (int e = 0; e < 8; ++e) {
      const bool alive = (rem >> e) & 1u;
      const float v = tv[e];
      const int ix = ti[e];
      if (alive && (v > bv || (v == bv && ix < bi))) { bv = v; bi = ix; }
    }
#pragma unroll
    for (int off = 32; off > 0; off >>= 1) {
      const float ov = __shfl_down(bv, off);
      const int oi = __shfl_down(bi, off);
      if (ov > bv || (ov == bv && oi < bi)) { bv = ov; bi = oi; }
    }
    if (lane == 0) { wv4[wave] = bv; wi4[wave] = bi; }
    __syncthreads();
    if (tid == 0) {
      float gv = wv4[0];
      int gi = wi4[0];
#pragma unroll
      for (int w = 1; w < 4; ++w)
        if (wv4[w] > gv || (wv4[w] == gv && wi4[w] < gi)) { gv = wv4[w]; gi = wi4[w]; }
      winner = gi;
      cand16[p] = gi;
    }
    __syncthreads();
    const int wgi = winner;
#pragma unroll
    for (int e = 0; e < 8; ++e)
      if (ti[e] == wgi) rem &= ~(1u << e);
  }

  __shared__ double sval[TOPC];
  __shared__ int sidx[TOPC];

  const double* urow = U + (size_t)r * D_DIM + lane * 16;
  double uv[16];
#pragma unroll
  for (int i = 0; i < 8; ++i) {
    const double2 d2 = *(const double2*)(urow + i * 2);
    uv[i * 2] = d2.x;
    uv[i * 2 + 1] = d2.y;
  }
  const double qb = qbs;

  for (int c = wave; c < TOPC; c += 4) {
    const int ci = cand16[c];
    const float* mrow = mem + (size_t)ci * D_DIM + lane * 16;
    double acc = 0.0;
#pragma unroll
    for (int i = 0; i < 4; ++i) {
      const float4 mv = *(const float4*)(mrow + i * 4);
      acc = fma(uv[i * 4 + 0], (double)mv.x, acc);
      acc = fma(uv[i * 4 + 1], (double)mv.y, acc);
      acc = fma(uv[i * 4 + 2], (double)mv.z, acc);
      acc = fma(uv[i * 4 + 3], (double)mv.w, acc);
    }
#pragma unroll
    for (int off = 32; off > 0; off >>= 1) acc += __shfl_down(acc, off);
    if (lane == 0) { sval[c] = acc + qb; sidx[c] = ci; }
  }
  __syncthreads();

  if (tid == 0) {
    bool used[TOPC];
#pragma unroll
    for (int p = 0; p < TOPC; ++p) used[p] = false;
#pragma unroll
    for (int p = 0; p < TOPK; ++p) {
      int best = -1;
      double bv = 0.0;
      int bi = 0;
      for (int c = 0; c < TOPC; ++c) {
        if (used[c]) continue;
        const double v = sval[c];
        const int ix = sidx[c];
        if (best < 0 || v > bv || (v == bv && ix < bi)) { best = c; bv = v; bi = ix; }
      }
      used[best] = true;
      topi[(size_t)r * TOPK + p] = bi;
    }
  }
}

// ---------------------------------------------------------------------------
// Gather selected V rows (bf16) + LayerNorm in f32 (round-18-proven).
// ---------------------------------------------------------------------------
__global__ __launch_bounds__(256) void gather_ln(
    const unsigned short* __restrict__ V, const int* __restrict__ topi,
    const float* __restrict__ gamma, const float* __restrict__ beta,
    float* __restrict__ out)
{
  const int row = blockIdx.x;
  const int tid = threadIdx.x;
  const int idx = topi[row];
  const unsigned short* src = V + (size_t)idx * D_DIM;
  const ushort4 raw = *(const ushort4*)(src + tid * 4);
  const float v0 = bf16_to_f32(raw.x);
  const float v1 = bf16_to_f32(raw.y);
  const float v2 = bf16_to_f32(raw.z);
  const float v3 = bf16_to_f32(raw.w);
  float s = v0 + v1 + v2 + v3;
  float s2 = v0 * v0 + v1 * v1 + v2 * v2 + v3 * v3;
#pragma unroll
  for (int off = 32; off > 0; off >>= 1) {
    s += __shfl_down(s, off);
    s2 += __shfl_down(s2, off);
  }
  __shared__ float red[8];
  __shared__ float stats[2];
  const int wid = tid >> 6;
  if ((tid & 63) == 0) { red[wid] = s; red[4 + wid] = s2; }
  __syncthreads();
  if (tid == 0) {
    const float S = red[0] + red[1] + red[2] + red[3];
    const float S2 = red[4] + red[5] + red[6] + red[7];
    const float mu = S * (1.0f / D_DIM);
    const float var = S2 * (1.0f / D_DIM) - mu * mu;
    stats[0] = mu;
    stats[1] = rsqrtf(var + 1e-5f);
  }
  __syncthreads();
  const float mu = stats[0], rstd = stats[1];
  const float4 g4 = *(const float4*)(gamma + tid * 4);
  const float4 b4 = *(const float4*)(beta + tid * 4);
  float4 o;
  o.x = (v0 - mu) * rstd * g4.x + b4.x;
  o.y = (v1 - mu) * rstd * g4.y + b4.y;
  o.z = (v2 - mu) * rstd * g4.z + b4.z;
  o.w = (v3 - mu) * rstd * g4.w + b4.w;
  *(float4*)(out + (size_t)row * D_DIM + tid * 4) = o;
}

extern "C" void kernel_launch(void* const* d_in, const int* in_sizes, int n_in,
                              void* d_out, int out_size, void* d_ws, size_t ws_size,
                              hipStream_t stream)
{
  const float* query = (const float*)d_in[0];
  const float* mem   = (const float*)d_in[1];
  const float* Wq    = (const float*)d_in[2];
  const float* bq    = (const float*)d_in[3];
  const float* Wk    = (const float*)d_in[4];
  const float* bk    = (const float*)d_in[5];
  const float* Wv    = (const float*)d_in[6];
  const float* bv    = (const float*)d_in[7];
  const float* gamma = (const float*)d_in[8];
  const float* beta  = (const float*)d_in[9];
  float* out = (float*)d_out;

  char* ws = (char*)d_ws;
  double* u64 = (double*)ws;   ws += (size_t)B_ROWS * D_DIM * sizeof(double);      // 33.6 MB
  double* G = (double*)ws;     ws += (size_t)D_DIM * D_DIM * sizeof(double);       // 8.4 MB (dedicated now)
  unsigned short* qbf = (unsigned short*)ws;
  ws += (size_t)B_ROWS * D_DIM * sizeof(unsigned short);                           // 8.4 MB
  unsigned short* querybf = (unsigned short*)ws;
  ws += (size_t)B_ROWS * D_DIM * sizeof(unsigned short);                           // 8.4 MB
  unsigned short* membf = (unsigned short*)ws;
  ws += (size_t)M_ROWS * D_DIM * sizeof(unsigned short);                           // 67.1 MB
  unsigned short* wkbf = (unsigned short*)ws;
  ws += (size_t)D_DIM * D_DIM * sizeof(unsigned short);                            // 2.1 MB (dedicated)
  unsigned short* wvbf = (unsigned short*)ws;
  ws += (size_t)D_DIM * D_DIM * sizeof(unsigned short);                            // 2.1 MB
  unsigned short* wqbf = (unsigned short*)ws;
  ws += (size_t)D_DIM * D_DIM * sizeof(unsigned short);                            // 2.1 MB
  char* Aregion = ws;
  ws += (size_t)M_ROWS * D_DIM * sizeof(unsigned short)                            // Kbf 67.1
      + 2 * (size_t)B_ROWS * NCB * TOPB * sizeof(float);                           // parts 67.1
  double* wvec = (double*)ws;  ws += (size_t)D_DIM * sizeof(double);
  double* ubias = (double*)ws; ws += (size_t)D_DIM * sizeof(double);
  double* s0 = (double*)ws;    ws += 2 * sizeof(double);
  int* topi = (int*)ws;

  unsigned short* Kbf = (unsigned short*)Aregion;
  float* part_v = (float*)(Aregion + (size_t)M_ROWS * D_DIM * sizeof(unsigned short));
  int* part_i = (int*)((char*)part_v + (size_t)B_ROWS * NCB * TOPB * sizeof(float));
  unsigned short* Vbf = (unsigned short*)Aregion;

  // Fused: gram (G) + bias terms + ALL casts (concurrent; casts no longer
  // alias G). One launch fills the machine that 265-block gram left idle.
  gram_bias_cast<<<dim3(265 + NCAST_BLK), 256, 0, stream>>>(
      Wq, Wk, bq, bk, mem, query, Wv,
      G, wvec, ubias, s0, membf, querybf, wkbf, wvbf, wqbf);

  uproj_G<<<dim3(B_ROWS / 64, D_DIM / 64), 256, 0, stream>>>(query, G, ubias, u64);

  proj_kq_bf16<<<dim3((M_ROWS + B_ROWS) / 256, D_DIM / 128), 512, 0, stream>>>(
      membf, querybf, wkbf, wqbf, bk, bq, Kbf, qbf);

  sims_topc_gemm<<<dim3((B_ROWS / 256) * NCB), 512, 0, stream>>>(qbf, Kbf, part_v, part_i);
  merge_rescore<<<dim3(B_ROWS), 256, 0, stream>>>(part_v, part_i, u64, query, wvec, s0, mem, topi);

  // V path (bf16 out, overlays dead Kbf/parts region).
  proj256_bf16<<<dim3(M_ROWS / 256, D_DIM / 128), 512, 0, stream>>>(membf, wvbf, bv, Vbf);
  gather_ln<<<dim3(B_ROWS * TOPK), 256, 0, stream>>>(Vbf, topi, gamma, beta, out);
}

// Round 24
// 1037.575 us; speedup vs baseline: 7.7200x; 1.0141x over previous
//
#include <hip/hip_runtime.h>
#include <hip/hip_bf16.h>
#include <math.h>

#define D_DIM 1024
#define B_ROWS 4096
#define M_ROWS 32768
#define TOPK 8
#define TOPC 16
#define TOPB 8
#define NCB (M_ROWS / 128)

typedef __attribute__((ext_vector_type(8))) short bf16x8;
typedef __attribute__((ext_vector_type(4))) float f32x4;

__device__ __forceinline__ unsigned short f32_to_bf16(float f) {
  unsigned int u = __float_as_uint(f);
  unsigned int r = (u + 0x7FFFu + ((u >> 16) & 1u)) >> 16;
  return (unsigned short)r;
}
__device__ __forceinline__ float bf16_to_f32(unsigned short h) {
  return __uint_as_float(((unsigned int)h) << 16);
}
__device__ __forceinline__ void async_copy16(void* lds, const void* g) {
  __builtin_amdgcn_global_load_lds(
      (const __attribute__((address_space(1))) unsigned int*)g,
      (__attribute__((address_space(3))) unsigned int*)lds, 16, 0, 0);
}

template <int N>
__device__ __forceinline__ void insN(float v, int idx,
                                     float* __restrict__ tv,
                                     int* __restrict__ ti) {
  if (v < tv[N - 1]) return;
  if (v == tv[N - 1] && idx > ti[N - 1]) return;
  float cv = v;
  int ci = idx;
#pragma unroll
  for (int p = 0; p < N; ++p) {
    if (cv > tv[p] || (cv == tv[p] && ci < ti[p])) {
      const float t0 = tv[p]; tv[p] = cv; cv = t0;
      const int t1 = ti[p]; ti[p] = ci; ci = t1;
    }
  }
}

#define N4_MEM   (M_ROWS * D_DIM / 4)
#define N4_QUERY (B_ROWS * D_DIM / 4)
#define N4_W     (D_DIM * D_DIM / 4)
#define N4_TOTAL (N4_MEM + N4_QUERY + 3 * N4_W)
#define NCAST_BLK ((N4_TOTAL + 255) / 256)

// ---------------------------------------------------------------------------
// FUSED gram + bias terms + casts (round-23-proven).
// ---------------------------------------------------------------------------
__global__ __launch_bounds__(256) void gram_bias_cast(
    const float* __restrict__ Wq, const float* __restrict__ Wk,
    const float* __restrict__ bq, const float* __restrict__ bk,
    const float* __restrict__ mem, const float* __restrict__ query,
    const float* __restrict__ Wv,
    double* __restrict__ G, double* __restrict__ wvec,
    double* __restrict__ ubias, double* __restrict__ s0,
    unsigned short* __restrict__ membf, unsigned short* __restrict__ querybf,
    unsigned short* __restrict__ wkbf, unsigned short* __restrict__ wvbf,
    unsigned short* __restrict__ wqbf)
{
  __shared__ float sA[2][32][68];
  __shared__ float sB[2][32][68];
  const int blk = blockIdx.x;
  const int tid = threadIdx.x;

  if (blk < 256) {
    const int tx = tid & 15, ty = tid >> 4;
    const int f0 = (blk >> 4) * 64;
    const int e0 = (blk & 15) * 64;

    double acc[4][4];
#pragma unroll
    for (int i = 0; i < 4; ++i)
#pragma unroll
      for (int j = 0; j < 4; ++j) acc[i][j] = 0.0;

    auto STAGE = [&](int d, int k0) {
#pragma unroll
      for (int it = 0; it < 2; ++it) {
        const int L = it * 256 + tid;
        const int kk = L >> 4, c4 = (L & 15) * 4;
        *(float4*)&sA[d][kk][c4] = *(const float4*)(Wq + (size_t)(k0 + kk) * D_DIM + f0 + c4);
        *(float4*)&sB[d][kk][c4] = *(const float4*)(Wk + (size_t)(k0 + kk) * D_DIM + e0 + c4);
      }
    };

    STAGE(0, 0);
    __syncthreads();
    int cur = 0;
    for (int t = 0; t < 32; ++t) {
      if (t < 31) STAGE(cur ^ 1, (t + 1) * 32);
#pragma unroll
      for (int kk = 0; kk < 32; ++kk) {
        const double a[4] = {sA[cur][kk][ty * 4 + 0], sA[cur][kk][ty * 4 + 1],
                             sA[cur][kk][ty * 4 + 2], sA[cur][kk][ty * 4 + 3]};
        const double b[4] = {sB[cur][kk][tx * 4 + 0], sB[cur][kk][tx * 4 + 1],
                             sB[cur][kk][tx * 4 + 2], sB[cur][kk][tx * 4 + 3]};
#pragma unroll
        for (int i = 0; i < 4; ++i)
#pragma unroll
          for (int j = 0; j < 4; ++j)
            acc[i][j] = fma(a[i], b[j], acc[i][j]);
      }
      __syncthreads();
      cur ^= 1;
    }
#pragma unroll
    for (int i = 0; i < 4; ++i)
#pragma unroll
      for (int j = 0; j < 4; ++j)
        G[(size_t)(f0 + ty * 4 + i) * D_DIM + e0 + tx * 4 + j] = acc[i][j];
  } else if (blk < 260) {
    const int c = (blk - 256) * 256 + tid;
    double acc = 0.0;
    for (int n = 0; n < D_DIM; ++n)
      acc = fma((double)Wq[(size_t)n * D_DIM + c], (double)bk[n], acc);
    wvec[c] = acc;
  } else if (blk < 264) {
    const int c = (blk - 260) * 256 + tid;
    double acc = 0.0;
    for (int n = 0; n < D_DIM; ++n)
      acc = fma((double)Wk[(size_t)n * D_DIM + c], (double)bq[n], acc);
    ubias[c] = acc;
  } else if (blk == 264) {
    double acc = 0.0;
#pragma unroll
    for (int i = 0; i < 4; ++i) {
      const int idx = tid * 4 + i;
      acc = fma((double)bq[idx], (double)bk[idx], acc);
    }
#pragma unroll
    for (int off = 32; off > 0; off >>= 1) acc += __shfl_down(acc, off);
    __shared__ double red[4];
    if ((tid & 63) == 0) red[tid >> 6] = acc;
    __syncthreads();
    if (tid == 0) s0[0] = red[0] + red[1] + red[2] + red[3];
  } else {
    int i = (blk - 265) * 256 + tid;
    if (i >= N4_TOTAL) return;
    const float* src;
    unsigned short* dst;
    if (i < N4_MEM) { src = mem; dst = membf; }
    else if ((i -= N4_MEM) < N4_QUERY) { src = query; dst = querybf; }
    else if ((i -= N4_QUERY) < N4_W) { src = Wk; dst = wkbf; }
    else if ((i -= N4_W) < N4_W) { src = Wv; dst = wvbf; }
    else { i -= N4_W; src = Wq; dst = wqbf; }
    const float4 v = *(const float4*)(src + (size_t)i * 4);
    ushort4 o;
    o.x = f32_to_bf16(v.x);
    o.y = f32_to_bf16(v.y);
    o.z = f32_to_bf16(v.z);
    o.w = f32_to_bf16(v.w);
    *(ushort4*)(dst + (size_t)i * 4) = o;
  }
}

// ---------------------------------------------------------------------------
// u[b,d] = sum_e query[b,e]*G[e,d] + ubias[d], f64 (round-20/21-proven dbuf).
// ---------------------------------------------------------------------------
__global__ __launch_bounds__(256) void uproj_G(
    const float* __restrict__ query, const double* __restrict__ G,
    const double* __restrict__ ubias, double* __restrict__ U)
{
  __shared__ double sAdT[2][32][66];
  __shared__ double sBd[2][32][68];
  const int tid = threadIdx.x;
  const int tx = tid & 15, ty = tid >> 4;
  const int row0 = blockIdx.x * 64;
  const int col0 = blockIdx.y * 64;

  double acc[4][4];
#pragma unroll
  for (int i = 0; i < 4; ++i)
#pragma unroll
    for (int j = 0; j < 4; ++j) acc[i][j] = 0.0;

  auto STAGE = [&](int d, int k0) {
#pragma unroll
    for (int it = 0; it < 2; ++it) {
      const int L = it * 256 + tid;
      const int rowa = L >> 3, c4 = (L & 7) * 4;
      const float4 v =
          *(const float4*)(query + (size_t)(row0 + rowa) * D_DIM + k0 + c4);
      sAdT[d][c4 + 0][rowa] = (double)v.x;
      sAdT[d][c4 + 1][rowa] = (double)v.y;
      sAdT[d][c4 + 2][rowa] = (double)v.z;
      sAdT[d][c4 + 3][rowa] = (double)v.w;
    }
#pragma unroll
    for (int it = 0; it < 4; ++it) {
      const int L = it * 256 + tid;
      const int kk = L >> 5, c2 = (L & 31) * 2;
      *(double2*)&sBd[d][kk][c2] =
          *(const double2*)(G + (size_t)(k0 + kk) * D_DIM + col0 + c2);
    }
  };

  STAGE(0, 0);
  __syncthreads();
  int cur = 0;
  for (int t = 0; t < 32; ++t) {
    if (t < 31) STAGE(cur ^ 1, (t + 1) * 32);
#pragma unroll
    for (int kk = 0; kk < 32; ++kk) {
      const double2 p0 = *(const double2*)&sAdT[cur][kk][ty * 4];
      const double2 p1 = *(const double2*)&sAdT[cur][kk][ty * 4 + 2];
      const double a[4] = {p0.x, p0.y, p1.x, p1.y};
      const double bb[4] = {sBd[cur][kk][tx * 4 + 0], sBd[cur][kk][tx * 4 + 1],
                            sBd[cur][kk][tx * 4 + 2], sBd[cur][kk][tx * 4 + 3]};
#pragma unroll
      for (int i = 0; i < 4; ++i)
#pragma unroll
        for (int j = 0; j < 4; ++j)
          acc[i][j] = fma(a[i], bb[j], acc[i][j]);
    }
    __syncthreads();
    cur ^= 1;
  }
  const double ub[4] = {ubias[col0 + tx * 4 + 0], ubias[col0 + tx * 4 + 1],
                        ubias[col0 + tx * 4 + 2], ubias[col0 + tx * 4 + 3]};
#pragma unroll
  for (int i = 0; i < 4; ++i) {
    const size_t base = (size_t)(row0 + ty * 4 + i) * D_DIM + col0 + tx * 4;
    *(double2*)(U + base)     = (double2){acc[i][0] + ub[0], acc[i][1] + ub[1]};
    *(double2*)(U + base + 2) = (double2){acc[i][2] + ub[2], acc[i][3] + ub[3]};
  }
}

// ---------------------------------------------------------------------------
// Fused sims + per-half top-4 (rounds 18-23 proven). Round-24: epilogue packs
// each candidate as uint = (bf16 value << 16) | local_col (0..127); parts
// shrink 67 -> 33.5 MB. Value round-trip exact (tv came from bf16);
// tie semantics preserved (merge reconstructs global idx = cb*128 + loc).
// ---------------------------------------------------------------------------
#define SBUF3 12288
__global__ __launch_bounds__(512, 4) void sims_topc_gemm(
    const unsigned short* __restrict__ A, const unsigned short* __restrict__ B,
    unsigned int* __restrict__ parts)
{
  __shared__ unsigned short smem[3 * SBUF3];

  const int tid = threadIdx.x;
  const int lane = tid & 63;
  const int wave = tid >> 6;
  const int wr = wave >> 1;
  const int wc = wave & 1;

  const int bid = blockIdx.x;
  const int x = bid & 7;
  const int t9 = bid >> 3;
  const int cbg = t9 >> 7;
  const int r = (t9 >> 3) & 15;
  const int cbl = t9 & 7;
  const int cb = (x * 4 + cbg) * 8 + cbl;
  const int row0 = r * 256;
  const int col0 = cb * 128;

  const int st_r = lane >> 2;
  const int st_swz = ((lane & 3) ^ ((st_r >> 1) & 3)) * 16;

  auto STAGE = [&](int d, int k0) {
    unsigned short* buf = smem + d * SBUF3;
#pragma unroll
    for (int i = 0; i < 3; ++i) {
      const int seg = wave * 3 + i;
      if (seg < 16) {
        const int grow = row0 + seg * 16 + st_r;
        async_copy16((char*)(buf + seg * 512),
                     (const char*)(A + (size_t)grow * D_DIM + k0) + st_swz);
      } else {
        const int s2 = seg - 16;
        const int grow = col0 + s2 * 16 + st_r;
        async_copy16((char*)(buf + 8192 + s2 * 512),
                     (const char*)(B + (size_t)grow * D_DIM + k0) + st_swz);
      }
    }
  };

  f32x4 acc[4][4];
#pragma unroll
  for (int m = 0; m < 4; ++m)
#pragma unroll
    for (int n = 0; n < 4; ++n) acc[m][n] = (f32x4){0.f, 0.f, 0.f, 0.f};

  auto COMPUTE = [&](int d) {
    const unsigned short* sA = smem + d * SBUF3;
    const unsigned short* sB = sA + 8192;
    bf16x8 af[4], bfr[4];
    const int ch = lane >> 4;
#pragma unroll
    for (int m = 0; m < 4; ++m) {
      const int Ra = wr * 64 + m * 16 + (lane & 15);
      af[m] = *(const bf16x8*)((const char*)sA + Ra * 64 + ((ch ^ ((Ra >> 1) & 3)) * 16));
    }
#pragma unroll
    for (int n = 0; n < 4; ++n) {
      const int Rb = wc * 64 + n * 16 + (lane & 15);
      bfr[n] = *(const bf16x8*)((const char*)sB + Rb * 64 + ((ch ^ ((Rb >> 1) & 3)) * 16));
    }
    __builtin_amdgcn_s_setprio(1);
#pragma unroll
    for (int m = 0; m < 4; ++m)
#pragma unroll
      for (int n = 0; n < 4; ++n)
        acc[m][n] = __builtin_amdgcn_mfma_f32_16x16x32_bf16(af[m], bfr[n], acc[m][n], 0, 0, 0);
    __builtin_amdgcn_s_setprio(0);
  };

  STAGE(0, 0);
  STAGE(1, 32);
  asm volatile("s_waitcnt vmcnt(3)" ::: "memory");
  __builtin_amdgcn_sched_barrier(0);
  __builtin_amdgcn_s_barrier();

  for (int tt = 0; tt < 30; tt += 3) {
    STAGE(2, (tt + 2) * 32);
    COMPUTE(0);
    asm volatile("s_waitcnt vmcnt(3)" ::: "memory");
    __builtin_amdgcn_sched_barrier(0);
    __builtin_amdgcn_s_barrier();

    STAGE(0, (tt + 3) * 32);
    COMPUTE(1);
    asm volatile("s_waitcnt vmcnt(3)" ::: "memory");
    __builtin_amdgcn_sched_barrier(0);
    __builtin_amdgcn_s_barrier();

    STAGE(1, (tt + 4) * 32);
    COMPUTE(2);
    asm volatile("s_waitcnt vmcnt(3)" ::: "memory");
    __builtin_amdgcn_sched_barrier(0);
    __builtin_amdgcn_s_barrier();
  }
  COMPUTE(0);
  asm volatile("s_waitcnt vmcnt(0)" ::: "memory");
  __builtin_amdgcn_sched_barrier(0);
  __builtin_amdgcn_s_barrier();
  COMPUTE(1);
  __builtin_amdgcn_sched_barrier(0);
  __builtin_amdgcn_s_barrier();

#pragma unroll
  for (int m = 0; m < 4; ++m)
#pragma unroll
    for (int n = 0; n < 4; ++n)
#pragma unroll
      for (int rg = 0; rg < 4; ++rg) {
        const int row = wr * 64 + m * 16 + (lane >> 4) * 4 + rg;
        const int colL = wc * 64 + n * 16 + (lane & 15);
        smem[row * 132 + colL] = f32_to_bf16(acc[m][n][rg]);
      }
  __syncthreads();

  {
    const int row = tid & 255;
    const int h = tid >> 8;
    float tv[4];
    int ti_[4];
#pragma unroll
    for (int p = 0; p < 4; ++p) { tv[p] = -INFINITY; ti_[p] = 0; }
    const unsigned short* crow = smem + row * 132 + h * 64;
    const int lbase = h * 64;   // local col base within the 128-col block
    for (int j = 0; j < 64; j += 4) {
      const ushort4 c4 = *(const ushort4*)(crow + j);
      insN<4>(bf16_to_f32(c4.x), lbase + j + 0, tv, ti_);
      insN<4>(bf16_to_f32(c4.y), lbase + j + 1, tv, ti_);
      insN<4>(bf16_to_f32(c4.z), lbase + j + 2, tv, ti_);
      insN<4>(bf16_to_f32(c4.w), lbase + j + 3, tv, ti_);
    }
    uint4 pk;
    pk.x = ((unsigned)f32_to_bf16(tv[0]) << 16) | (unsigned)ti_[0];
    pk.y = ((unsigned)f32_to_bf16(tv[1]) << 16) | (unsigned)ti_[1];
    pk.z = ((unsigned)f32_to_bf16(tv[2]) << 16) | (unsigned)ti_[2];
    pk.w = ((unsigned)f32_to_bf16(tv[3]) << 16) | (unsigned)ti_[3];
    const size_t base = ((size_t)(row0 + row) * NCB + cb) * TOPB + h * 4;
    *(uint4*)(parts + base) = pk;
  }
}

// ---------------------------------------------------------------------------
// FUSED K + q + V projection (round-24): 3-way row-space concatenation.
// bx < 128 -> K (mem x Wk -> Kbf); bx < 144 -> q (query x Wq -> qbf);
// else -> V (mem x Wv -> Vbf, dedicated region). Body = proven proj256.
// ---------------------------------------------------------------------------
__global__ __launch_bounds__(512, 4) void proj_kqv_bf16(
    const unsigned short* __restrict__ Amem,
    const unsigned short* __restrict__ Aquery,
    const unsigned short* __restrict__ Bk,
    const unsigned short* __restrict__ Bq,
    const unsigned short* __restrict__ Bv,
    const float* __restrict__ bk_, const float* __restrict__ bq_,
    const float* __restrict__ bv_,
    unsigned short* __restrict__ Ck, unsigned short* __restrict__ Cq,
    unsigned short* __restrict__ Cv)
{
  __shared__ unsigned short smem[3 * SBUF3];

  const int tid = threadIdx.x;
  const int lane = tid & 63;
  const int wave = tid >> 6;
  const int wr = wave >> 1;
  const int wc = wave & 1;

  const int bx = blockIdx.x;
  const unsigned short* A;
  const unsigned short* B;
  const float* bias;
  unsigned short* C;
  int row0;
  if (bx < M_ROWS / 256) {
    A = Amem; B = Bk; bias = bk_; C = Ck; row0 = bx * 256;
  } else if (bx < M_ROWS / 256 + B_ROWS / 256) {
    A = Aquery; B = Bq; bias = bq_; C = Cq; row0 = (bx - M_ROWS / 256) * 256;
  } else {
    A = Amem; B = Bv; bias = bv_; C = Cv;
    row0 = (bx - M_ROWS / 256 - B_ROWS / 256) * 256;
  }
  const int col0 = blockIdx.y * 128;

  const int st_r = lane >> 2;
  const int st_swz = ((lane & 3) ^ ((st_r >> 1) & 3)) * 16;

  auto STAGE = [&](int d, int k0) {
    unsigned short* buf = smem + d * SBUF3;
#pragma unroll
    for (int i = 0; i < 3; ++i) {
      const int seg = wave * 3 + i;
      if (seg < 16) {
        const int grow = row0 + seg * 16 + st_r;
        async_copy16((char*)(buf + seg * 512),
                     (const char*)(A + (size_t)grow * D_DIM + k0) + st_swz);
      } else {
        const int s2 = seg - 16;
        const int grow = col0 + s2 * 16 + st_r;
        async_copy16((char*)(buf + 8192 + s2 * 512),
                     (const char*)(B + (size_t)grow * D_DIM + k0) + st_swz);
      }
    }
  };

  f32x4 acc[4][4];
#pragma unroll
  for (int m = 0; m < 4; ++m)
#pragma unroll
    for (int n = 0; n < 4; ++n) acc[m][n] = (f32x4){0.f, 0.f, 0.f, 0.f};

  auto COMPUTE = [&](int d) {
    const unsigned short* sA = smem + d * SBUF3;
    const unsigned short* sB = sA + 8192;
    bf16x8 af[4], bfr[4];
    const int ch = lane >> 4;
#pragma unroll
    for (int m = 0; m < 4; ++m) {
      const int Ra = wr * 64 + m * 16 + (lane & 15);
      af[m] = *(const bf16x8*)((const char*)sA + Ra * 64 + ((ch ^ ((Ra >> 1) & 3)) * 16));
    }
#pragma unroll
    for (int n = 0; n < 4; ++n) {
      const int Rb = wc * 64 + n * 16 + (lane & 15);
      bfr[n] = *(const bf16x8*)((const char*)sB + Rb * 64 + ((ch ^ ((Rb >> 1) & 3)) * 16));
    }
    __builtin_amdgcn_s_setprio(1);
#pragma unroll
    for (int m = 0; m < 4; ++m)
#pragma unroll
      for (int n = 0; n < 4; ++n)
        acc[m][n] = __builtin_amdgcn_mfma_f32_16x16x32_bf16(af[m], bfr[n], acc[m][n], 0, 0, 0);
    __builtin_amdgcn_s_setprio(0);
  };

  STAGE(0, 0);
  STAGE(1, 32);
  asm volatile("s_waitcnt vmcnt(3)" ::: "memory");
  __builtin_amdgcn_sched_barrier(0);
  __builtin_amdgcn_s_barrier();

  for (int tt = 0; tt < 30; tt += 3) {
    STAGE(2, (tt + 2) * 32);
    COMPUTE(0);
    asm volatile("s_waitcnt vmcnt(3)" ::: "memory");
    __builtin_amdgcn_sched_barrier(0);
    __builtin_amdgcn_s_barrier();

    STAGE(0, (tt + 3) * 32);
    COMPUTE(1);
    asm volatile("s_waitcnt vmcnt(3)" ::: "memory");
    __builtin_amdgcn_sched_barrier(0);
    __builtin_amdgcn_s_barrier();

    STAGE(1, (tt + 4) * 32);
    COMPUTE(2);
    asm volatile("s_waitcnt vmcnt(3)" ::: "memory");
    __builtin_amdgcn_sched_barrier(0);
    __builtin_amdgcn_s_barrier();
  }
  COMPUTE(0);
  asm volatile("s_waitcnt vmcnt(0)" ::: "memory");
  __builtin_amdgcn_sched_barrier(0);
  __builtin_amdgcn_s_barrier();
  COMPUTE(1);

#pragma unroll
  for (int n = 0; n < 4; ++n) {
    const int col = col0 + wc * 64 + n * 16 + (lane & 15);
    const float bcol = bias[col];
#pragma unroll
    for (int m = 0; m < 4; ++m)
#pragma unroll
      for (int rg = 0; rg < 4; ++rg) {
        const int row = row0 + wr * 64 + m * 16 + (lane >> 4) * 4 + rg;
        C[(size_t)row * D_DIM + col] = f32_to_bf16(acc[m][n][rg] + bcol);
      }
  }
}

// ---------------------------------------------------------------------------
// FUSED merge + rescore + qbk (round-22/23-proven; phase-1 unpacks the
// round-24 packed parts: global idx = cb*128 + loc, value = bf16).
// ---------------------------------------------------------------------------
__global__ __launch_bounds__(256) void merge_rescore(
    const unsigned int* __restrict__ parts,
    const double* __restrict__ U, const float* __restrict__ query,
    const double* __restrict__ wvec, const double* __restrict__ s0,
    const float* __restrict__ mem, int* __restrict__ topi)
{
  const int r = blockIdx.x;
  const int tid = threadIdx.x;
  const int lane = tid & 63;
  const int wave = tid >> 6;

  __shared__ double qred[4];
  __shared__ double qbs;
  {
    const float* qrow = query + (size_t)r * D_DIM + tid * 4;
    const double* wrow = wvec + tid * 4;
    double qa = 0.0;
#pragma unroll
    for (int i = 0; i < 4; ++i)
      qa = fma((double)qrow[i], wrow[i], qa);
#pragma unroll
    for (int off = 32; off > 0; off >>= 1) qa += __shfl_down(qa, off);
    if (lane == 0) qred[wave] = qa;
    __syncthreads();
    if (tid == 0) qbs = qred[0] + qred[1] + qred[2] + qred[3] + s0[0];
  }

  float tv[8];
  int ti[8];
  {
    const size_t base = ((size_t)r * NCB + tid) * TOPB;
    const uint4 w0 = *(const uint4*)(parts + base);
    const uint4 w1 = *(const uint4*)(parts + base + 4);
    const int gb = tid * 128;   // thread tid IS cb
    tv[0] = bf16_to_f32((unsigned short)(w0.x >> 16)); ti[0] = gb + (int)(w0.x & 0xFFFFu);
    tv[1] = bf16_to_f32((unsigned short)(w0.y >> 16)); ti[1] = gb + (int)(w0.y & 0xFFFFu);
    tv[2] = bf16_to_f32((unsigned short)(w0.z >> 16)); ti[2] = gb + (int)(w0.z & 0xFFFFu);
    tv[3] = bf16_to_f32((unsigned short)(w0.w >> 16)); ti[3] = gb + (int)(w0.w & 0xFFFFu);
    tv[4] = bf16_to_f32((unsigned short)(w1.x >> 16)); ti[4] = gb + (int)(w1.x & 0xFFFFu);
    tv[5] = bf16_to_f32((unsigned short)(w1.y >> 16)); ti[5] = gb + (int)(w1.y & 0xFFFFu);
    tv[6] = bf16_to_f32((unsigned short)(w1.z >> 16)); ti[6] = gb + (int)(w1.z & 0xFFFFu);
    tv[7] = bf16_to_f32((unsigned short)(w1.w >> 16)); ti[7] = gb + (int)(w1.w & 0xFFFFu);
  }
  unsigned rem = 0xFFu;

  __shared__ float wv4[4];
  __shared__ int wi4[4];
  __shared__ int winner;
  __shared__ int cand16[TOPC];

  for (int p = 0; p < TOPC; ++p) {
    float bv = -INFINITY;
    int bi = 0x7FFFFFFF;
#pragma unroll
    for (int e = 0; e < 8; ++e) {
      const bool alive = (rem >> e) & 1u;
      const float v = tv[e];
      const int ix = ti[e];
      if (alive && (v > bv || (v == bv && ix < bi))) { bv = v; bi = ix; }
    }
#pragma unroll
    for (int off = 32; off > 0; off >>= 1) {
      const float ov = __shfl_down(bv, off);
      const int oi = __shfl_down(bi, off);
      if (ov > bv || (ov == bv && oi < bi)) { bv = ov; bi = oi; }
    }
    if (lane == 0) { wv4[wave] = bv; wi4[wave] = bi; }
    __syncthreads();
    if (tid == 0) {
      float gv = wv4[0];
      int gi = wi4[0];
#pragma unroll
      for (int w = 1; w < 4; ++w)
        if (wv4[w] > gv || (wv4[w] == gv && wi4[w] < gi)) { gv = wv4[w]; gi = wi4[w]; }
      winner = gi;
      cand16[p] = gi;
    }
    __syncthreads();
    const int wgi = winner;
#pragma unroll
    for (int e = 0; e < 8; ++e)
      if (ti[e] == wgi) rem &= ~(1u << e);
  }

  __shared__ double sval[TOPC];
  __shared__ int sidx[TOPC];

  const double* urow = U + (size_t)r * D_DIM + lane * 16;
  double uv[16];
#pragma unroll
  for (int i = 0; i < 8; ++i) {
    const double2 d2 = *(const double2*)(urow + i * 2);
    uv[i * 2] = d2.x;
    uv[i * 2 + 1] = d2.y;
  }
  const double qb = qbs;

  for (int c = wave; c < TOPC; c += 4) {
    const int ci = cand16[c];
    const float* mrow = mem + (size_t)ci * D_DIM + lane * 16;
    double acc = 0.0;
#pragma unroll
    for (int i = 0; i < 4; ++i) {
      const float4 mv = *(const float4*)(mrow + i * 4);
      acc = fma(uv[i * 4 + 0], (double)mv.x, acc);
      acc = fma(uv[i * 4 + 1], (double)mv.y, acc);
      acc = fma(uv[i * 4 + 2], (double)mv.z, acc);
      acc = fma(uv[i * 4 + 3], (double)mv.w, acc);
    }
#pragma unroll
    for (int off = 32; off > 0; off >>= 1) acc += __shfl_down(acc, off);
    if (lane == 0) { sval[c] = acc + qb; sidx[c] = ci; }
  }
  __syncthreads();

  if (tid == 0) {
    bool used[TOPC];
#pragma unroll
    for (int p = 0; p < TOPC; ++p) used[p] = false;
#pragma unroll
    for (int p = 0; p < TOPK; ++p) {
      int best = -1;
      double bv = 0.0;
      int bi = 0;
      for (int c = 0; c < TOPC; ++c) {
        if (used[c]) continue;
        const double v = sval[c];
        const int ix = sidx[c];
        if (best < 0 || v > bv || (v == bv && ix < bi)) { best = c; bv = v; bi = ix; }
      }
      used[best] = true;
      topi[(size_t)r * TOPK + p] = bi;
    }
  }
}

// ---------------------------------------------------------------------------
// Gather selected V rows (bf16) + LayerNorm in f32 (round-18-proven).
// ---------------------------------------------------------------------------
__global__ __launch_bounds__(256) void gather_ln(
    const unsigned short* __restrict__ V, const int* __restrict__ topi,
    const float* __restrict__ gamma, const float* __restrict__ beta,
    float* __restrict__ out)
{
  const int row = blockIdx.x;
  const int tid = threadIdx.x;
  const int idx = topi[row];
  const unsigned short* src = V + (size_t)idx * D_DIM;
  const ushort4 raw = *(const ushort4*)(src + tid * 4);
  const float v0 = bf16_to_f32(raw.x);
  const float v1 = bf16_to_f32(raw.y);
  const float v2 = bf16_to_f32(raw.z);
  const float v3 = bf16_to_f32(raw.w);
  float s = v0 + v1 + v2 + v3;
  float s2 = v0 * v0 + v1 * v1 + v2 * v2 + v3 * v3;
#pragma unroll
  for (int off = 32; off > 0; off >>= 1) {
    s += __shfl_down(s, off);
    s2 += __shfl_down(s2, off);
  }
  __shared__ float red[8];
  __shared__ float stats[2];
  const int wid = tid >> 6;
  if ((tid & 63) == 0) { red[wid] = s; red[4 + wid] = s2; }
  __syncthreads();
  if (tid == 0) {
    const float S = red[0] + red[1] + red[2] + red[3];
    const float S2 = red[4] + red[5] + red[6] + red[7];
    const float mu = S * (1.0f / D_DIM);
    const float var = S2 * (1.0f / D_DIM) - mu * mu;
    stats[0] = mu;
    stats[1] = rsqrtf(var + 1e-5f);
  }
  __syncthreads();
  const float mu = stats[0], rstd = stats[1];
  const float4 g4 = *(const float4*)(gamma + tid * 4);
  const float4 b4 = *(const float4*)(beta + tid * 4);
  float4 o;
  o.x = (v0 - mu) * rstd * g4.x + b4.x;
  o.y = (v1 - mu) * rstd * g4.y + b4.y;
  o.z = (v2 - mu) * rstd * g4.z + b4.z;
  o.w = (v3 - mu) * rstd * g4.w + b4.w;
  *(float4*)(out + (size_t)row * D_DIM + tid * 4) = o;
}

extern "C" void kernel_launch(void* const* d_in, const int* in_sizes, int n_in,
                              void* d_out, int out_size, void* d_ws, size_t ws_size,
                              hipStream_t stream)
{
  const float* query = (const float*)d_in[0];
  const float* mem   = (const float*)d_in[1];
  const float* Wq    = (const float*)d_in[2];
  const float* bq    = (const float*)d_in[3];
  const float* Wk    = (const float*)d_in[4];
  const float* bk    = (const float*)d_in[5];
  const float* Wv    = (const float*)d_in[6];
  const float* bv    = (const float*)d_in[7];
  const float* gamma = (const float*)d_in[8];
  const float* beta  = (const float*)d_in[9];
  float* out = (float*)d_out;

  // Layout (291.7 MB total; <= 294 MB proven in round 8):
  char* ws = (char*)d_ws;
  double* u64 = (double*)ws;   ws += (size_t)B_ROWS * D_DIM * sizeof(double);      // 33.6 MB
  double* G = (double*)ws;     ws += (size_t)D_DIM * D_DIM * sizeof(double);       // 8.4 MB
  unsigned short* qbf = (unsigned short*)ws;
  ws += (size_t)B_ROWS * D_DIM * sizeof(unsigned short);                           // 8.4 MB
  unsigned short* membf = (unsigned short*)ws;
  ws += (size_t)M_ROWS * D_DIM * sizeof(unsigned short);                           // 67.1 MB
  unsigned short* wkbf = (unsigned short*)ws;
  ws += (size_t)D_DIM * D_DIM * sizeof(unsigned short);                            // 2.1 MB
  unsigned short* wvbf = (unsigned short*)ws;
  ws += (size_t)D_DIM * D_DIM * sizeof(unsigned short);                            // 2.1 MB
  unsigned short* wqbf = (unsigned short*)ws;
  ws += (size_t)D_DIM * D_DIM * sizeof(unsigned short);                            // 2.1 MB
  unsigned short* Kbf = (unsigned short*)ws;
  ws += (size_t)M_ROWS * D_DIM * sizeof(unsigned short);                           // 67.1 MB
  unsigned short* Vbf = (unsigned short*)ws;
  ws += (size_t)M_ROWS * D_DIM * sizeof(unsigned short);                           // 67.1 MB (dedicated)
  unsigned int* parts = (unsigned int*)ws;
  ws += (size_t)B_ROWS * NCB * TOPB * sizeof(unsigned int);                        // 33.6 MB (packed)
  double* wvec = (double*)ws;  ws += (size_t)D_DIM * sizeof(double);
  double* ubias = (double*)ws; ws += (size_t)D_DIM * sizeof(double);
  double* s0 = (double*)ws;    ws += 2 * sizeof(double);
  int* topi = (int*)ws;

  // querybf overlays the parts region (written k1, read proj_kqv, dead
  // before sims writes parts).
  unsigned short* querybf = (unsigned short*)parts;

  // 1) gram (G) + bias terms + ALL casts (concurrent machine fill).
  gram_bias_cast<<<dim3(265 + NCAST_BLK), 256, 0, stream>>>(
      Wq, Wk, bq, bk, mem, query, Wv,
      G, wvec, ubias, s0, membf, querybf, wkbf, wvbf, wqbf);

  // 2) u = query@G + ubias (f64 selection chain).
  uproj_G<<<dim3(B_ROWS / 64, D_DIM / 64), 256, 0, stream>>>(query, G, ubias, u64);

  // 3) K + q + V projections in one launch (V -> dedicated Vbf).
  proj_kqv_bf16<<<dim3((2 * M_ROWS + B_ROWS) / 256, D_DIM / 128), 512, 0, stream>>>(
      membf, querybf, wkbf, wqbf, wvbf, bk, bq, bv, Kbf, qbf, Vbf);

  // 4) sims + packed per-block top-4x2.
  sims_topc_gemm<<<dim3((B_ROWS / 256) * NCB), 512, 0, stream>>>(qbf, Kbf, parts);

  // 5) merge + fp64 rescore + qbk.
  merge_rescore<<<dim3(B_ROWS), 256, 0, stream>>>(parts, u64, query, wvec, s0, mem, topi);

  // 6) gather + LayerNorm.
  gather_ln<<<dim3(B_ROWS * TOPK), 256, 0, stream>>>(Vbf, topi, gamma, beta, out);
}